// Round 2
// baseline (1739.922 us; speedup 1.0000x reference)
//
#include <hip/hip_runtime.h>

// ---------------------------------------------------------------------------
// SwinTransformerBlock fused kernel, MI355X / gfx950.
// Runtime dtype detection (device probe): inputs/outputs either all-bf16 or
// all-fp32; compute path is bf16 MFMA either way.
// One workgroup (256 thr = 4 waves) per 7x7 window; 8192 windows.
// ---------------------------------------------------------------------------

typedef __bf16 bf16;
typedef __attribute__((ext_vector_type(8))) __bf16 bf16x8;
typedef __attribute__((ext_vector_type(4))) float f32x4;

#define LDA 104   // row stride (elems) for [64][*] bf16 tiles
#define LDV 72    // row stride for V^T [96][*]
#define LDP 72    // row stride for per-wave P [16][*]

__device__ __forceinline__ f32x4 mfma16(bf16x8 a, bf16x8 b, f32x4 c) {
    return __builtin_amdgcn_mfma_f32_16x16x32_bf16(a, b, c, 0, 0, 0);
}

__device__ __forceinline__ float ldf(const void* p, size_t i, bool ibf) {
    return ibf ? (float)((const bf16*)p)[i] : ((const float*)p)[i];
}

// ---------------- dtype probe ----------------------------------------------
// Even u16 slots of a bf16 array are real bf16 values (sane exponents).
// Even u16 slots of an fp32 array are mantissa bits (uniform exponents).
__global__ void dtype_probe(const void* x, int* flag) {
    const unsigned short* u = (const unsigned short*)x;
    unsigned short h = u[threadIdx.x * 2];
    int e = (h >> 7) & 0xFF;
    bool sane = ((h & 0x7FFF) == 0) || (e >= 96 && e <= 150);
    unsigned long long m = __ballot(sane);
    if (threadIdx.x == 0) flag[0] = (__popcll(m) >= 48) ? 1 : 0;
}

// ---------------- weight pre-transpose into workspace ----------------------
// wsT layout (bf16 elems): qkvT[288][96] @0, projT[96][96] @27648,
//                          fc1T[384][96] @36864, fc2T[96][384] @73728
__global__ void swin_wprep(const void* qkv_w, const void* proj_w,
                           const void* fc1_w, const void* fc2_w,
                           bf16* __restrict__ wsT, const int* flag, int flag_ok) {
    const bool ibf = flag_ok ? (flag[0] != 0) : true;
    int i = blockIdx.x * 256 + threadIdx.x;
    if (i < 27648) {
        int n = i / 96, k = i - n * 96;
        wsT[i] = (bf16)ldf(qkv_w, (size_t)k * 288 + n, ibf);
    } else if (i < 36864) {
        int j = i - 27648;
        int n = j / 96, k = j - n * 96;
        wsT[i] = (bf16)ldf(proj_w, (size_t)k * 96 + n, ibf);
    } else if (i < 73728) {
        int j = i - 36864;
        int n = j / 96, k = j - n * 96;
        wsT[i] = (bf16)ldf(fc1_w, (size_t)k * 384 + n, ibf);
    } else if (i < 110592) {
        int j = i - 73728;
        int n = j / 384, k = j - n * 384;
        wsT[i] = (bf16)ldf(fc2_w, (size_t)k * 96 + n, ibf);
    }
}

// B-fragment load: transposed workspace (fast) or strided original (fallback)
__device__ __forceinline__ bf16x8 load_bfragT(const bf16* T, const void* worig,
                                              int nrow, int k0, int K, int N,
                                              bool ibf, bool wok) {
    if (wok) return *(const bf16x8*)(T + (size_t)nrow * K + k0);
    bf16x8 f;
#pragma unroll
    for (int j = 0; j < 8; ++j)
        f[j] = (bf16)ldf(worig, (size_t)(k0 + j) * N + nrow, ibf);
    return f;
}

// ---------------------------- fused block ----------------------------------
__global__ __launch_bounds__(256)
void swin_fused(const void* __restrict__ x,
                const void* __restrict__ n1w, const void* __restrict__ n1b,
                const void* __restrict__ qkvw, const void* __restrict__ qkvb,
                const void* __restrict__ projw, const void* __restrict__ projb,
                const void* __restrict__ n2w, const void* __restrict__ n2b,
                const void* __restrict__ fc1w, const void* __restrict__ fc1b,
                const void* __restrict__ fc2w, const void* __restrict__ fc2b,
                const bf16* __restrict__ wsT, const int* __restrict__ flag,
                int flag_ok, int w_ok,
                void* __restrict__ out) {
    __shared__ __attribute__((aligned(16))) bf16 sA[64 * LDA]; // raw -> attn O
    __shared__ __attribute__((aligned(16))) bf16 sB[64 * LDA]; // Q -> t2
    __shared__ __attribute__((aligned(16))) bf16 sC[64 * LDA]; // K -> hidden -> final
    __shared__ __attribute__((aligned(16))) bf16 sV[96 * LDV]; // V^T [d][token]
    __shared__ __attribute__((aligned(16))) bf16 sP[4][16 * LDP];
    __shared__ float sMu[64], sRs[64], sMu2[64], sRs2[64];

    const bool ibf = flag_ok ? (flag[0] != 0) : true;
    const bool wok = (w_ok != 0);

    const int tid  = threadIdx.x;
    const int wave = tid >> 6;
    const int lane = tid & 63;
    const int g    = lane >> 4;
    const int q16  = lane & 15;

    const int wid = blockIdx.x;
    const int b  = wid >> 10;
    const int wy = (wid >> 5) & 31;
    const int wx = wid & 31;
    const int h0 = wy * 7, w0 = wx * 7;

    // ---- P0: load window into sA (row = token ty*7+tx, col = c)
    for (int u = tid; u < 672; u += 256) {
        int c = u / 7, ty = u - c * 7;
        size_t base = ((size_t)(b * 96 + c) * 224 + (h0 + ty)) * 224 + w0;
        bf16* dst = &sA[(ty * 7) * LDA + c];
#pragma unroll
        for (int tx = 0; tx < 7; ++tx) dst[tx * LDA] = (bf16)ldf(x, base + tx, ibf);
    }
    for (int u = tid; u < 15 * 96; u += 256) {   // zero pad rows 49..63
        int r = u / 96, c = u - r * 96;
        sA[(49 + r) * LDA + c] = (bf16)0.f;
    }
    __syncthreads();

    // ---- P1: LN1 stats
    {
        int r = tid >> 2, part = tid & 3;
        const bf16* row = &sA[r * LDA + part * 24];
        float s = 0.f, s2 = 0.f;
#pragma unroll
        for (int j = 0; j < 24; ++j) { float v = (float)row[j]; s += v; s2 += v * v; }
        s += __shfl_xor(s, 1);  s2 += __shfl_xor(s2, 1);
        s += __shfl_xor(s, 2);  s2 += __shfl_xor(s2, 2);
        if (part == 0) {
            float mu  = s * (1.f / 96.f);
            float var = s2 * (1.f / 96.f) - mu * mu;
            sMu[r] = mu;
            sRs[r] = rsqrtf(fmaxf(var, 0.f) + 1e-5f);
        }
    }
    __syncthreads();

    // ---- P2: QKV GEMM (N-split across waves), LN1 on the fly
    bf16x8 afrag[3][4];
#pragma unroll
    for (int s = 0; s < 3; ++s) {
        const int c0 = s * 32 + g * 8;
        float wv[8], bv[8];
#pragma unroll
        for (int j = 0; j < 8; ++j) { wv[j] = ldf(n1w, c0 + j, ibf); bv[j] = ldf(n1b, c0 + j, ibf); }
#pragma unroll
        for (int m = 0; m < 4; ++m) {
            int row = m * 16 + q16;
            float mu = sMu[row], rs = sRs[row];
            bf16x8 raw = *(const bf16x8*)&sA[row * LDA + c0];
            bf16x8 f;
#pragma unroll
            for (int j = 0; j < 8; ++j)
                f[j] = (bf16)(((float)raw[j] - mu) * rs * wv[j] + bv[j]);
            afrag[s][m] = f;
        }
    }

    const bf16* qkvT  = wsT;
    const bf16* projT = wsT + 27648;
    const bf16* fc1T  = wsT + 36864;
    const bf16* fc2T  = wsT + 73728;

    for (int nt = wave; nt < 18; nt += 4) {
        const int nrow = nt * 16 + q16;
        f32x4 acc[4] = {{0,0,0,0},{0,0,0,0},{0,0,0,0},{0,0,0,0}};
#pragma unroll
        for (int s = 0; s < 3; ++s) {
            bf16x8 bfrag = load_bfragT(qkvT, qkvw, nrow, s * 32 + g * 8, 96, 288, ibf, wok);
#pragma unroll
            for (int m = 0; m < 4; ++m) acc[m] = mfma16(afrag[s][m], bfrag, acc[m]);
        }
        float bias = ldf(qkvb, nrow, ibf);
#pragma unroll
        for (int m = 0; m < 4; ++m) {
#pragma unroll
            for (int r = 0; r < 4; ++r) {
                float v = acc[m][r] + bias;
                int row = m * 16 + g * 4 + r;
                bf16 hv = (bf16)v;
                if (nrow < 96)        sB[row * LDA + nrow] = hv;             // Q
                else if (nrow < 192)  sC[row * LDA + (nrow - 96)] = hv;      // K
                else                  sV[(nrow - 192) * LDV + row] = hv;     // V^T
            }
        }
    }

    // shortcut for this wave's output tiles (read before sA is reused)
    const int npt = (wave < 2) ? 2 : 1;
    float shc[2][4][4];
#pragma unroll
    for (int t = 0; t < 2; ++t) {
        if (t < npt) {
            int col = ((t == 0) ? wave : wave + 4) * 16 + q16;
#pragma unroll
            for (int m = 0; m < 4; ++m)
#pragma unroll
                for (int r = 0; r < 4; ++r)
                    shc[t][m][r] = (float)sA[(m * 16 + g * 4 + r) * LDA + col];
        }
    }
    __syncthreads();

    // ---- P3: attention (wave = one 16-query tile, all 3 heads)
    const float sc_l2e = 0.17677669529663688f * 1.4426950408889634f;
    bf16* myP = sP[wave];
#pragma unroll
    for (int h = 0; h < 3; ++h) {
        bf16x8 aq = *(const bf16x8*)&sB[(wave * 16 + q16) * LDA + h * 32 + g * 8];
        f32x4 s4[4];
#pragma unroll
        for (int kt = 0; kt < 4; ++kt) {
            bf16x8 bk = *(const bf16x8*)&sC[(kt * 16 + q16) * LDA + h * 32 + g * 8];
            f32x4 z = {0, 0, 0, 0};
            s4[kt] = mfma16(aq, bk, z);
        }
        float inv[4];
#pragma unroll
        for (int r = 0; r < 4; ++r) {
            float m0 = -1e30f;
#pragma unroll
            for (int kt = 0; kt < 4; ++kt) {
                float v = (kt * 16 + q16 < 49) ? s4[kt][r] : -1e30f;
                m0 = fmaxf(m0, v);
            }
            m0 = fmaxf(m0, __shfl_xor(m0, 1));
            m0 = fmaxf(m0, __shfl_xor(m0, 2));
            m0 = fmaxf(m0, __shfl_xor(m0, 4));
            m0 = fmaxf(m0, __shfl_xor(m0, 8));
            float ss = 0.f;
#pragma unroll
            for (int kt = 0; kt < 4; ++kt) {
                float e = (kt * 16 + q16 < 49) ? exp2f((s4[kt][r] - m0) * sc_l2e) : 0.f;
                s4[kt][r] = e;
                ss += e;
            }
            ss += __shfl_xor(ss, 1);
            ss += __shfl_xor(ss, 2);
            ss += __shfl_xor(ss, 4);
            ss += __shfl_xor(ss, 8);
            inv[r] = 1.f / fmaxf(ss, 1e-30f);
        }
#pragma unroll
        for (int kt = 0; kt < 4; ++kt)
#pragma unroll
            for (int r = 0; r < 4; ++r)
                myP[(g * 4 + r) * LDP + kt * 16 + q16] = (bf16)s4[kt][r];
        bf16x8 ap0 = *(const bf16x8*)&myP[q16 * LDP + g * 8];
        bf16x8 ap1 = *(const bf16x8*)&myP[q16 * LDP + 32 + g * 8];
#pragma unroll
        for (int n2 = 0; n2 < 2; ++n2) {
            int d0 = h * 32 + n2 * 16 + q16;
            bf16x8 bv0 = *(const bf16x8*)&sV[d0 * LDV + g * 8];
            bf16x8 bv1 = *(const bf16x8*)&sV[d0 * LDV + 32 + g * 8];
            f32x4 oa = {0, 0, 0, 0};
            oa = mfma16(ap0, bv0, oa);
            oa = mfma16(ap1, bv1, oa);
#pragma unroll
            for (int r = 0; r < 4; ++r) {
                float v = oa[r] * inv[r];
                sA[(wave * 16 + g * 4 + r) * LDA + h * 32 + n2 * 16 + q16] = (bf16)v;
            }
        }
    }
    __syncthreads();

    // ---- P4: proj (N-split), + shortcut -> t2 in sB
    bf16x8 ao[3][4];
#pragma unroll
    for (int s = 0; s < 3; ++s)
#pragma unroll
        for (int m = 0; m < 4; ++m)
            ao[s][m] = *(const bf16x8*)&sA[(m * 16 + q16) * LDA + s * 32 + g * 8];

    float t2v[2][4][4];
#pragma unroll
    for (int t = 0; t < 2; ++t) {
        if (t < npt) {
            int nt = (t == 0) ? wave : wave + 4;
            int nrow = nt * 16 + q16;
            f32x4 acc[4] = {{0,0,0,0},{0,0,0,0},{0,0,0,0},{0,0,0,0}};
#pragma unroll
            for (int s = 0; s < 3; ++s) {
                bf16x8 bfrag = load_bfragT(projT, projw, nrow, s * 32 + g * 8, 96, 96, ibf, wok);
#pragma unroll
                for (int m = 0; m < 4; ++m) acc[m] = mfma16(ao[s][m], bfrag, acc[m]);
            }
            float bias = ldf(projb, nrow, ibf);
#pragma unroll
            for (int m = 0; m < 4; ++m)
#pragma unroll
                for (int r = 0; r < 4; ++r) {
                    float v = acc[m][r] + bias + shc[t][m][r];
                    t2v[t][m][r] = v;
                    sB[(m * 16 + g * 4 + r) * LDA + nrow] = (bf16)v;
                }
        }
    }
    __syncthreads();

    // ---- LN2 stats
    {
        int r = tid >> 2, part = tid & 3;
        const bf16* row = &sB[r * LDA + part * 24];
        float s = 0.f, s2 = 0.f;
#pragma unroll
        for (int j = 0; j < 24; ++j) { float v = (float)row[j]; s += v; s2 += v * v; }
        s += __shfl_xor(s, 1);  s2 += __shfl_xor(s2, 1);
        s += __shfl_xor(s, 2);  s2 += __shfl_xor(s2, 2);
        if (part == 0) {
            float mu  = s * (1.f / 96.f);
            float var = s2 * (1.f / 96.f) - mu * mu;
            sMu2[r] = mu;
            sRs2[r] = rsqrtf(fmaxf(var, 0.f) + 1e-5f);
        }
    }
    __syncthreads();

    // ---- P5: MLP (fc1 + GELU + fc2), LN2 on the fly
    bf16x8 am[3][4];
#pragma unroll
    for (int s = 0; s < 3; ++s) {
        const int c0 = s * 32 + g * 8;
        float wv[8], bv[8];
#pragma unroll
        for (int j = 0; j < 8; ++j) { wv[j] = ldf(n2w, c0 + j, ibf); bv[j] = ldf(n2b, c0 + j, ibf); }
#pragma unroll
        for (int m = 0; m < 4; ++m) {
            int row = m * 16 + q16;
            float mu = sMu2[row], rs = sRs2[row];
            bf16x8 raw = *(const bf16x8*)&sB[row * LDA + c0];
            bf16x8 f;
#pragma unroll
            for (int j = 0; j < 8; ++j)
                f[j] = (bf16)(((float)raw[j] - mu) * rs * wv[j] + bv[j]);
            am[s][m] = f;
        }
    }

    f32x4 f2acc[2][4] = {{{0,0,0,0},{0,0,0,0},{0,0,0,0},{0,0,0,0}},
                         {{0,0,0,0},{0,0,0,0},{0,0,0,0},{0,0,0,0}}};
    for (int ch = 0; ch < 4; ++ch) {
#pragma unroll
        for (int t = 0; t < 2; ++t) {
            if (t < npt) {
                int ntl = (t == 0) ? wave : wave + 4;
                int nrow = (ch * 6 + ntl) * 16 + q16;
                f32x4 acc[4] = {{0,0,0,0},{0,0,0,0},{0,0,0,0},{0,0,0,0}};
#pragma unroll
                for (int s = 0; s < 3; ++s) {
                    bf16x8 bfrag = load_bfragT(fc1T, fc1w, nrow, s * 32 + g * 8, 96, 384, ibf, wok);
#pragma unroll
                    for (int m = 0; m < 4; ++m) acc[m] = mfma16(am[s][m], bfrag, acc[m]);
                }
                float bias = ldf(fc1b, nrow, ibf);
#pragma unroll
                for (int m = 0; m < 4; ++m)
#pragma unroll
                    for (int r = 0; r < 4; ++r) {
                        float v = acc[m][r] + bias;
                        v = 0.5f * v * (1.f + erff(v * 0.70710678118f));
                        sC[(m * 16 + g * 4 + r) * LDA + ntl * 16 + q16] = (bf16)v;
                    }
            }
        }
        __syncthreads();
        bf16x8 ah[3][4];
#pragma unroll
        for (int s = 0; s < 3; ++s)
#pragma unroll
            for (int m = 0; m < 4; ++m)
                ah[s][m] = *(const bf16x8*)&sC[(m * 16 + q16) * LDA + s * 32 + g * 8];
#pragma unroll
        for (int t = 0; t < 2; ++t) {
            if (t < npt) {
                int nt = (t == 0) ? wave : wave + 4;
                int nrow = nt * 16 + q16;
#pragma unroll
                for (int s = 0; s < 3; ++s) {
                    bf16x8 bfrag = load_bfragT(fc2T, fc2w, nrow, ch * 96 + s * 32 + g * 8, 384, 96, ibf, wok);
#pragma unroll
                    for (int m = 0; m < 4; ++m) f2acc[t][m] = mfma16(ah[s][m], bfrag, f2acc[t][m]);
                }
            }
        }
        __syncthreads();
    }

    // ---- final epilogue -> sC
#pragma unroll
    for (int t = 0; t < 2; ++t) {
        if (t < npt) {
            int col = ((t == 0) ? wave : wave + 4) * 16 + q16;
            float bias = ldf(fc2b, col, ibf);
#pragma unroll
            for (int m = 0; m < 4; ++m)
#pragma unroll
                for (int r = 0; r < 4; ++r) {
                    float v = f2acc[t][m][r] + bias + t2v[t][m][r];
                    sC[(m * 16 + g * 4 + r) * LDA + col] = (bf16)v;
                }
        }
    }
    __syncthreads();

    // ---- scatter back to [B, C, H, W]
    for (int u = tid; u < 672; u += 256) {
        int c = u / 7, ty = u - c * 7;
        size_t base = ((size_t)(b * 96 + c) * 224 + (h0 + ty)) * 224 + w0;
        const bf16* srcr = &sC[(ty * 7) * LDA + c];
        if (ibf) {
            bf16* o = (bf16*)out;
#pragma unroll
            for (int tx = 0; tx < 7; ++tx) o[base + tx] = srcr[tx * LDA];
        } else {
            float* o = (float*)out;
#pragma unroll
            for (int tx = 0; tx < 7; ++tx) o[base + tx] = (float)srcr[tx * LDA];
        }
    }
}

// ---------------------------------------------------------------------------
extern "C" void kernel_launch(void* const* d_in, const int* in_sizes, int n_in,
                              void* d_out, int out_size, void* d_ws, size_t ws_size,
                              hipStream_t stream) {
    const void* x      = d_in[0];
    const void* n1w    = d_in[1];
    const void* n1b    = d_in[2];
    const void* qkv_w  = d_in[3];
    const void* qkv_b  = d_in[4];
    const void* proj_w = d_in[5];
    const void* proj_b = d_in[6];
    const void* n2w    = d_in[7];
    const void* n2b    = d_in[8];
    const void* fc1_w  = d_in[9];
    const void* fc1_b  = d_in[10];
    const void* fc2_w  = d_in[11];
    const void* fc2_b  = d_in[12];

    const int flag_ok = (ws_size >= 64) ? 1 : 0;
    const int w_ok    = (ws_size >= 64 + 221184) ? 1 : 0;
    int*  flag = (int*)d_ws;
    bf16* wsT  = (bf16*)((char*)d_ws + 64);

    if (flag_ok)
        dtype_probe<<<dim3(1), dim3(64), 0, stream>>>(x, flag);
    if (w_ok)
        swin_wprep<<<dim3(432), dim3(256), 0, stream>>>(qkv_w, proj_w, fc1_w, fc2_w,
                                                        wsT, flag, flag_ok);

    swin_fused<<<dim3(8192), dim3(256), 0, stream>>>(
        x, n1w, n1b, qkv_w, qkv_b, proj_w, proj_b, n2w, n2b,
        fc1_w, fc1_b, fc2_w, fc2_b, wsT, flag, flag_ok, w_ok, (void*)d_out);
}

// Round 3
// 812.673 us; speedup vs baseline: 2.1410x; 2.1410x over previous
//
#include <hip/hip_runtime.h>

// ---------------------------------------------------------------------------
// SwinTransformerBlock, MI355X / gfx950. fp32 I/O (confirmed), bf16 MFMA core.
// Pipeline: wprep (weights->bf16 transposed)
//           K0 padfill -> K1 gather (CHW fp32 -> windowed tokens bf16)
//           K2 fused block (per 7x7 window, in-place on token buffer)
//           K3 scatter (windowed tokens bf16 -> CHW fp32)
// Fallback: if ws too small, K2 gathers/scatters x/out directly.
// ---------------------------------------------------------------------------

typedef __bf16 bf16;
typedef __attribute__((ext_vector_type(8))) __bf16 bf16x8;
typedef __attribute__((ext_vector_type(4))) float f32x4;
typedef __attribute__((ext_vector_type(4))) int i32x4;

#define LDA 104      // row stride (elems) for [64][*] LDS tiles
#define LDV 72       // row stride for V^T [96][*]
#define LDW 233      // K1/K3 transpose-tile stride (odd -> bank spread)
#define TOKW 6144    // 64*96 elems per window

__device__ __forceinline__ f32x4 mfma16(bf16x8 a, bf16x8 b, f32x4 c) {
    return __builtin_amdgcn_mfma_f32_16x16x32_bf16(a, b, c, 0, 0, 0);
}

// ---------------- weight pre-transpose (fp32 -> bf16 [N][K]) ---------------
// wsT: qkvT[288][96] @0, projT[96][96] @27648, fc1T[384][96] @36864,
//      fc2T[96][384] @73728   (110592 elems)
__global__ void swin_wprep(const float* __restrict__ qkv_w,
                           const float* __restrict__ proj_w,
                           const float* __restrict__ fc1_w,
                           const float* __restrict__ fc2_w,
                           bf16* __restrict__ wsT) {
    int i = blockIdx.x * 256 + threadIdx.x;
    if (i < 27648) { int n = i / 96, k = i - n * 96; wsT[i] = (bf16)qkv_w[k * 288 + n]; }
    else if (i < 36864) { int j = i - 27648, n = j / 96, k = j - n * 96; wsT[i] = (bf16)proj_w[k * 96 + n]; }
    else if (i < 73728) { int j = i - 36864, n = j / 96, k = j - n * 96; wsT[i] = (bf16)fc1_w[k * 384 + n]; }
    else if (i < 110592){ int j = i - 73728, n = j / 384, k = j - n * 384; wsT[i] = (bf16)fc2_w[k * 96 + n]; }
}

// ---------------- K0: zero pad rows 49..63 of every window -----------------
__global__ void swin_padfill(bf16* __restrict__ tokW) {
    int id = blockIdx.x * 256 + threadIdx.x;          // 8192*180 exact
    int win = id / 180, r = id - win * 180;
    int row = 49 + r / 12, c8 = r - (r / 12) * 12;
    *(i32x4*)(tokW + (size_t)win * TOKW + row * 96 + c8 * 8) = i32x4{0, 0, 0, 0};
}

// ---------------- K1: x[B,C,H,W] fp32 -> tokW[win][64][96] bf16 ------------
__global__ __launch_bounds__(256)
void swin_gather(const float* __restrict__ x, bf16* __restrict__ tokW) {
    __shared__ bf16 sT[96 * LDW];                     // sT[c][w]
    const int tid = threadIdx.x;
    const int bi = blockIdx.x;                        // 0..1791
    const int b = bi / 224, h = bi - b * 224;
    const int wy = h / 7, ty = h - wy * 7;
    const size_t xbase = (size_t)b * 4816896 + (size_t)h * 224;  // + c*50176 + w

    // phase A: coalesced float4 reads along w, write sT[c][w]
#pragma unroll
    for (int i = 0; i < 21; ++i) {                    // 96*56 = 5376 = 21*256
        int id = i * 256 + tid;
        int c = id / 56, w4 = id - c * 56;
        f32x4 v = *(const f32x4*)(x + xbase + (size_t)c * 50176 + w4 * 4);
#pragma unroll
        for (int j = 0; j < 4; ++j) sT[c * LDW + w4 * 4 + j] = (bf16)v[j];
    }
    __syncthreads();

    // phase B: write contiguous 1344B spans per window (rows ty*7..ty*7+6)
#pragma unroll
    for (int i = 0; i < 11; ++i) {                    // 32*84 = 2688 chunks
        int id = i * 256 + tid;
        if (id < 2688) {
            int win = id / 84, r = id - win * 84;
            int tx = r / 12, c8 = r - tx * 12;
            bf16x8 v;
#pragma unroll
            for (int j = 0; j < 8; ++j) v[j] = sT[(c8 * 8 + j) * LDW + win * 7 + tx];
            *(i32x4*)(tokW + (size_t)(b * 1024 + wy * 32 + win) * TOKW
                      + (ty * 7 + tx) * 96 + c8 * 8) = *(i32x4*)&v;
        }
    }
}

// ---------------- K3: tokW[win][64][96] bf16 -> out[B,C,H,W] fp32 ----------
__global__ __launch_bounds__(256)
void swin_scatter(const bf16* __restrict__ tokW, float* __restrict__ out) {
    __shared__ bf16 sT[96 * LDW];
    const int tid = threadIdx.x;
    const int bi = blockIdx.x;
    const int b = bi / 224, h = bi - b * 224;
    const int wy = h / 7, ty = h - wy * 7;
    const size_t obase = (size_t)b * 4816896 + (size_t)h * 224;

#pragma unroll
    for (int i = 0; i < 11; ++i) {
        int id = i * 256 + tid;
        if (id < 2688) {
            int win = id / 84, r = id - win * 84;
            int tx = r / 12, c8 = r - tx * 12;
            bf16x8 v = *(const bf16x8*)(tokW + (size_t)(b * 1024 + wy * 32 + win) * TOKW
                                        + (ty * 7 + tx) * 96 + c8 * 8);
#pragma unroll
            for (int j = 0; j < 8; ++j) sT[(c8 * 8 + j) * LDW + win * 7 + tx] = v[j];
        }
    }
    __syncthreads();

#pragma unroll
    for (int i = 0; i < 21; ++i) {
        int id = i * 256 + tid;
        int c = id / 56, w4 = id - c * 56;
        f32x4 v;
#pragma unroll
        for (int j = 0; j < 4; ++j) v[j] = (float)sT[c * LDW + w4 * 4 + j];
        *(f32x4*)(out + obase + (size_t)c * 50176 + w4 * 4) = v;
    }
}

// B-fragment load: transposed bf16 workspace or strided fp32 fallback
__device__ __forceinline__ bf16x8 bload(const bf16* T, const float* worig,
                                        int nrow, int k0, int K, int N, bool wok) {
    if (wok) return *(const bf16x8*)(T + (size_t)nrow * K + k0);
    bf16x8 f;
#pragma unroll
    for (int j = 0; j < 8; ++j) f[j] = (bf16)worig[(size_t)(k0 + j) * N + nrow];
    return f;
}

// ---------------------------- K2: fused block ------------------------------
__global__ __launch_bounds__(256, 3)
void swin_fused(const float* __restrict__ x, bf16* __restrict__ tokW,
                const float* __restrict__ n1w, const float* __restrict__ n1b,
                const float* __restrict__ qkvw, const float* __restrict__ qkvb,
                const float* __restrict__ projw, const float* __restrict__ projb,
                const float* __restrict__ n2w, const float* __restrict__ n2b,
                const float* __restrict__ fc1w, const float* __restrict__ fc1b,
                const float* __restrict__ fc2w, const float* __restrict__ fc2b,
                const bf16* __restrict__ wsT,
                float* __restrict__ out, int fast_i, int wok_i) {
    // 53760 B pool + 512 B stats = 54272 B -> 3 blocks/CU
    __shared__ __attribute__((aligned(16))) bf16 L[26880];
    __shared__ float sStat[128];
    bf16* RA = L;              // raw tokens -> P-staging/O roundtrip
    bf16* RB = L + 6656;       // Q -> t2
    bf16* RC = L + 13312;      // K -> hidden chunks
    bf16* RV = L + 19968;      // V^T [96][LDV] -> final output [64][LDA]

    const bool fast = fast_i != 0;
    const bool wok  = wok_i != 0;

    const int tid  = threadIdx.x;
    const int wave = tid >> 6;
    const int lane = tid & 63;
    const int g    = lane >> 4;
    const int q16  = lane & 15;

    const int win = blockIdx.x;
    const int b  = win >> 10;
    const int wy = (win >> 5) & 31;
    const int wx = win & 31;
    const int h0 = wy * 7, w0 = wx * 7;
    const size_t xbase = (size_t)b * 4816896;   // + c*50176 + h*224 + w
    const bf16* myWin = tokW + (size_t)win * TOKW;

    // ---- P0: window -> RA
    if (fast) {
#pragma unroll
        for (int i = 0; i < 3; ++i) {             // 64*12 = 768 = 3*256
            int id = i * 256 + tid;
            int row = id / 12, c8 = id - row * 12;
            *(i32x4*)&RA[row * LDA + c8 * 8] = *(const i32x4*)(myWin + row * 96 + c8 * 8);
        }
    } else {
        for (int i = 0; i < 24; ++i) {            // 6144 elems
            int id = i * 256 + tid;
            if (id < 4704) {
                int c = id / 49, pix = id - c * 49;
                int ty = pix / 7, tx = pix - ty * 7;
                RA[pix * LDA + c] =
                    (bf16)x[xbase + (size_t)c * 50176 + (h0 + ty) * 224 + w0 + tx];
            } else {
                int j = id - 4704;
                int row = 49 + j / 96, c = j - (j / 96) * 96;
                RA[row * LDA + c] = (bf16)0.f;
            }
        }
    }
    __syncthreads();

    // ---- LN1 stats (vectorized: 3x b128 per lane)
    {
        int r = tid >> 2, p = tid & 3;
        float s = 0.f, s2 = 0.f;
#pragma unroll
        for (int v8 = 0; v8 < 3; ++v8) {
            bf16x8 v = *(const bf16x8*)&RA[r * LDA + p * 24 + v8 * 8];
#pragma unroll
            for (int j = 0; j < 8; ++j) { float f = (float)v[j]; s += f; s2 += f * f; }
        }
        s += __shfl_xor(s, 1);  s2 += __shfl_xor(s2, 1);
        s += __shfl_xor(s, 2);  s2 += __shfl_xor(s2, 2);
        if (p == 0) {
            float mu  = s * (1.f / 96.f);
            float var = s2 * (1.f / 96.f) - mu * mu;
            sStat[r]      = mu;
            sStat[64 + r] = rsqrtf(fmaxf(var, 0.f) + 1e-5f);
        }
    }
    __syncthreads();

    // ---- QKV GEMM (N-split), LN1 on the fly; A-frags in regs
    bf16x8 afrag[3][4];
#pragma unroll
    for (int s = 0; s < 3; ++s) {
        const int c0 = s * 32 + g * 8;
        float wv[8], bv[8];
#pragma unroll
        for (int j = 0; j < 8; ++j) { wv[j] = n1w[c0 + j]; bv[j] = n1b[c0 + j]; }
#pragma unroll
        for (int m = 0; m < 4; ++m) {
            int row = m * 16 + q16;
            float mu = sStat[row], rs = sStat[64 + row];
            bf16x8 raw = *(const bf16x8*)&RA[row * LDA + c0];
            bf16x8 f;
#pragma unroll
            for (int j = 0; j < 8; ++j)
                f[j] = (bf16)(((float)raw[j] - mu) * rs * wv[j] + bv[j]);
            afrag[s][m] = f;
        }
    }

    const bf16* qkvT  = wsT;
    const bf16* projT = wsT + 27648;
    const bf16* fc1T  = wsT + 36864;
    const bf16* fc2T  = wsT + 73728;

    for (int nt = wave; nt < 18; nt += 4) {
        const int nrow = nt * 16 + q16;
        f32x4 acc[4] = {{0,0,0,0},{0,0,0,0},{0,0,0,0},{0,0,0,0}};
#pragma unroll
        for (int s = 0; s < 3; ++s) {
            bf16x8 bf = bload(qkvT, qkvw, nrow, s * 32 + g * 8, 96, 288, wok);
#pragma unroll
            for (int m = 0; m < 4; ++m) acc[m] = mfma16(afrag[s][m], bf, acc[m]);
        }
        float bias = qkvb[nrow];
#pragma unroll
        for (int m = 0; m < 4; ++m)
#pragma unroll
            for (int r = 0; r < 4; ++r) {
                float v = acc[m][r] + bias;
                int row = m * 16 + g * 4 + r;
                bf16 hv = (bf16)v;
                if (nrow < 96)        RB[row * LDA + nrow] = hv;              // Q
                else if (nrow < 192)  RC[row * LDA + (nrow - 96)] = hv;       // K
                else                  RV[(nrow - 192) * LDV + row] = hv;      // V^T
            }
    }
    __syncthreads();   // Q/K/V ready; RA (raw) now dead -> P/O scratch

    // ---- attention: wave = one 16-query tile, 3 heads; O in registers
    const float sc_l2e = 0.17677669529663688f * 1.4426950408889634f;
    bf16* myP = RA + wave * 16 * LDA;
    f32x4 oacc[3][2];
#pragma unroll
    for (int h = 0; h < 3; ++h) {
        bf16x8 aq = *(const bf16x8*)&RB[(wave * 16 + q16) * LDA + h * 32 + g * 8];
        f32x4 s4[4];
#pragma unroll
        for (int kt = 0; kt < 4; ++kt) {
            bf16x8 bk = *(const bf16x8*)&RC[(kt * 16 + q16) * LDA + h * 32 + g * 8];
            f32x4 z = {0, 0, 0, 0};
            s4[kt] = mfma16(aq, bk, z);
        }
        float inv[4];
#pragma unroll
        for (int r = 0; r < 4; ++r) {
            float m0 = -1e30f;
#pragma unroll
            for (int kt = 0; kt < 4; ++kt) {
                float v = (kt * 16 + q16 < 49) ? s4[kt][r] : -1e30f;
                m0 = fmaxf(m0, v);
            }
            m0 = fmaxf(m0, __shfl_xor(m0, 1));
            m0 = fmaxf(m0, __shfl_xor(m0, 2));
            m0 = fmaxf(m0, __shfl_xor(m0, 4));
            m0 = fmaxf(m0, __shfl_xor(m0, 8));
            float ss = 0.f;
#pragma unroll
            for (int kt = 0; kt < 4; ++kt) {
                float e = (kt * 16 + q16 < 49) ? exp2f((s4[kt][r] - m0) * sc_l2e) : 0.f;
                s4[kt][r] = e;
                ss += e;
            }
            ss += __shfl_xor(ss, 1);
            ss += __shfl_xor(ss, 2);
            ss += __shfl_xor(ss, 4);
            ss += __shfl_xor(ss, 8);
            inv[r] = 1.f / fmaxf(ss, 1e-30f);
        }
#pragma unroll
        for (int kt = 0; kt < 4; ++kt)
#pragma unroll
            for (int r = 0; r < 4; ++r)
                myP[(g * 4 + r) * LDA + kt * 16 + q16] = (bf16)s4[kt][r];
        bf16x8 ap0 = *(const bf16x8*)&myP[q16 * LDA + g * 8];
        bf16x8 ap1 = *(const bf16x8*)&myP[q16 * LDA + 32 + g * 8];
#pragma unroll
        for (int n2 = 0; n2 < 2; ++n2) {
            int d0 = h * 32 + n2 * 16 + q16;
            bf16x8 bv0 = *(const bf16x8*)&RV[d0 * LDV + g * 8];
            bf16x8 bv1 = *(const bf16x8*)&RV[d0 * LDV + 32 + g * 8];
            f32x4 oa = {0, 0, 0, 0};
            oa = mfma16(ap0, bv0, oa);
            oa = mfma16(ap1, bv1, oa);
#pragma unroll
            for (int r = 0; r < 4; ++r) oa[r] *= inv[r];
            oacc[h][n2] = oa;
        }
    }
    // write O (C-layout) into own RA slice after all P reads
#pragma unroll
    for (int h = 0; h < 3; ++h)
#pragma unroll
        for (int n2 = 0; n2 < 2; ++n2)
#pragma unroll
            for (int r = 0; r < 4; ++r)
                myP[(g * 4 + r) * LDA + h * 32 + n2 * 16 + q16] = (bf16)oacc[h][n2][r];
    __syncthreads();   // O complete (RA), Q (RB) dead after this phase's reads

    // ---- proj (N-split) + shortcut -> t2 in RB
    bf16x8 ao[3][4];
#pragma unroll
    for (int s = 0; s < 3; ++s)
#pragma unroll
        for (int m = 0; m < 4; ++m)
            ao[s][m] = *(const bf16x8*)&RA[(m * 16 + q16) * LDA + s * 32 + g * 8];

    const int npt = (wave < 2) ? 2 : 1;
#pragma unroll
    for (int t = 0; t < 2; ++t) {
        if (t < npt) {
            int nt = (t == 0) ? wave : wave + 4;
            int nrow = nt * 16 + q16;
            f32x4 acc[4] = {{0,0,0,0},{0,0,0,0},{0,0,0,0},{0,0,0,0}};
#pragma unroll
            for (int s = 0; s < 3; ++s) {
                bf16x8 bf = bload(projT, projw, nrow, s * 32 + g * 8, 96, 96, wok);
#pragma unroll
                for (int m = 0; m < 4; ++m) acc[m] = mfma16(ao[s][m], bf, acc[m]);
            }
            float bias = projb[nrow];
#pragma unroll
            for (int m = 0; m < 4; ++m)
#pragma unroll
                for (int r = 0; r < 4; ++r) {
                    int row = m * 16 + g * 4 + r;
                    float sc;
                    if (fast) sc = (float)myWin[row * 96 + nrow];
                    else      sc = (row < 49)
                        ? x[xbase + (size_t)nrow * 50176 + (h0 + row / 7) * 224 + w0 + row % 7]
                        : 0.f;
                    float v = acc[m][r] + bias + sc;
                    RB[row * LDA + nrow] = (bf16)v;
                }
        }
    }
    __syncthreads();

    // ---- LN2 stats (t2 in RB)
    {
        int r = tid >> 2, p = tid & 3;
        float s = 0.f, s2 = 0.f;
#pragma unroll
        for (int v8 = 0; v8 < 3; ++v8) {
            bf16x8 v = *(const bf16x8*)&RB[r * LDA + p * 24 + v8 * 8];
#pragma unroll
            for (int j = 0; j < 8; ++j) { float f = (float)v[j]; s += f; s2 += f * f; }
        }
        s += __shfl_xor(s, 1);  s2 += __shfl_xor(s2, 1);
        s += __shfl_xor(s, 2);  s2 += __shfl_xor(s2, 2);
        if (p == 0) {
            float mu  = s * (1.f / 96.f);
            float var = s2 * (1.f / 96.f) - mu * mu;
            sStat[r]      = mu;
            sStat[64 + r] = rsqrtf(fmaxf(var, 0.f) + 1e-5f);
        }
    }
    __syncthreads();

    // ---- MLP: fc1 A-frags (LN2 on the fly) held across chunks
    bf16x8 am[3][4];
#pragma unroll
    for (int s = 0; s < 3; ++s) {
        const int c0 = s * 32 + g * 8;
        float wv[8], bv[8];
#pragma unroll
        for (int j = 0; j < 8; ++j) { wv[j] = n2w[c0 + j]; bv[j] = n2b[c0 + j]; }
#pragma unroll
        for (int m = 0; m < 4; ++m) {
            int row = m * 16 + q16;
            float mu = sStat[row], rs = sStat[64 + row];
            bf16x8 raw = *(const bf16x8*)&RB[row * LDA + c0];
            bf16x8 f;
#pragma unroll
            for (int j = 0; j < 8; ++j)
                f[j] = (bf16)(((float)raw[j] - mu) * rs * wv[j] + bv[j]);
            am[s][m] = f;
        }
    }

    f32x4 f2acc[2][4] = {{{0,0,0,0},{0,0,0,0},{0,0,0,0},{0,0,0,0}},
                         {{0,0,0,0},{0,0,0,0},{0,0,0,0},{0,0,0,0}}};
    for (int ch = 0; ch < 4; ++ch) {
#pragma unroll
        for (int t = 0; t < 2; ++t) {
            if (t < npt) {
                int ntl = (t == 0) ? wave : wave + 4;          // 0..5 (chunk-local)
                int nrow = (ch * 6 + ntl) * 16 + q16;
                f32x4 acc[4] = {{0,0,0,0},{0,0,0,0},{0,0,0,0},{0,0,0,0}};
#pragma unroll
                for (int s = 0; s < 3; ++s) {
                    bf16x8 bf = bload(fc1T, fc1w, nrow, s * 32 + g * 8, 96, 384, wok);
#pragma unroll
                    for (int m = 0; m < 4; ++m) acc[m] = mfma16(am[s][m], bf, acc[m]);
                }
                float bias = fc1b[nrow];
#pragma unroll
                for (int m = 0; m < 4; ++m)
#pragma unroll
                    for (int r = 0; r < 4; ++r) {
                        float v = acc[m][r] + bias;
                        v = 0.5f * v * (1.f + erff(v * 0.70710678118f));
                        RC[(m * 16 + g * 4 + r) * LDA + ntl * 16 + q16] = (bf16)v;
                    }
            }
        }
        __syncthreads();
        bf16x8 ah[3][4];
#pragma unroll
        for (int s = 0; s < 3; ++s)
#pragma unroll
            for (int m = 0; m < 4; ++m)
                ah[s][m] = *(const bf16x8*)&RC[(m * 16 + q16) * LDA + s * 32 + g * 8];
#pragma unroll
        for (int t = 0; t < 2; ++t) {
            if (t < npt) {
                int nt = (t == 0) ? wave : wave + 4;
                int nrow = nt * 16 + q16;
#pragma unroll
                for (int s = 0; s < 3; ++s) {
                    bf16x8 bf = bload(fc2T, fc2w, nrow, ch * 96 + s * 32 + g * 8, 384, 96, wok);
#pragma unroll
                    for (int m = 0; m < 4; ++m) f2acc[t][m] = mfma16(ah[s][m], bf, f2acc[t][m]);
                }
            }
        }
        __syncthreads();
    }

    // ---- final: out = t2 + fc2 + bias -> RV as [64][LDA]
#pragma unroll
    for (int t = 0; t < 2; ++t) {
        if (t < npt) {
            int col = ((t == 0) ? wave : wave + 4) * 16 + q16;
            float bias = fc2b[col];
#pragma unroll
            for (int m = 0; m < 4; ++m)
#pragma unroll
                for (int r = 0; r < 4; ++r) {
                    int row = m * 16 + g * 4 + r;
                    float t2 = (float)RB[row * LDA + col];
                    RV[row * LDA + col] = (bf16)(f2acc[t][m][r] + bias + t2);
                }
        }
    }
    __syncthreads();

    // ---- store (rows 0..48 only)
    if (fast) {
#pragma unroll
        for (int i = 0; i < 3; ++i) {                 // 49*12 = 588 chunks
            int id = i * 256 + tid;
            if (id < 588) {
                int row = id / 12, c8 = id - row * 12;
                *(i32x4*)(tokW + (size_t)win * TOKW + row * 96 + c8 * 8) =
                    *(const i32x4*)&RV[row * LDA + c8 * 8];
            }
        }
    } else {
        for (int i = 0; i < 19; ++i) {
            int id = i * 256 + tid;
            if (id < 4704) {
                int c = id / 49, pix = id - c * 49;
                int ty = pix / 7, tx = pix - ty * 7;
                out[xbase + (size_t)c * 50176 + (h0 + ty) * 224 + w0 + tx] =
                    (float)RV[pix * LDA + c];
            }
        }
    }
}

// ---------------------------------------------------------------------------
extern "C" void kernel_launch(void* const* d_in, const int* in_sizes, int n_in,
                              void* d_out, int out_size, void* d_ws, size_t ws_size,
                              hipStream_t stream) {
    const float* x      = (const float*)d_in[0];
    const float* n1w    = (const float*)d_in[1];
    const float* n1b    = (const float*)d_in[2];
    const float* qkv_w  = (const float*)d_in[3];
    const float* qkv_b  = (const float*)d_in[4];
    const float* proj_w = (const float*)d_in[5];
    const float* proj_b = (const float*)d_in[6];
    const float* n2w    = (const float*)d_in[7];
    const float* n2b    = (const float*)d_in[8];
    const float* fc1_w  = (const float*)d_in[9];
    const float* fc1_b  = (const float*)d_in[10];
    const float* fc2_w  = (const float*)d_in[11];
    const float* fc2_b  = (const float*)d_in[12];
    float* out = (float*)d_out;

    const size_t TOKW_OFF = 225280;                       // 221184 aligned up
    const int wok  = (ws_size >= 221184) ? 1 : 0;
    const int fast = (ws_size >= TOKW_OFF + 100663296ull) ? 1 : 0;
    bf16* wsT  = (bf16*)d_ws;
    bf16* tokW = (bf16*)((char*)d_ws + TOKW_OFF);

    if (wok)
        swin_wprep<<<dim3(432), dim3(256), 0, stream>>>(qkv_w, proj_w, fc1_w, fc2_w, wsT);
    if (fast) {
        swin_padfill<<<dim3(5760), dim3(256), 0, stream>>>(tokW);
        swin_gather<<<dim3(1792), dim3(256), 0, stream>>>(x, tokW);
    }
    swin_fused<<<dim3(8192), dim3(256), 0, stream>>>(
        x, tokW, n1w, n1b, qkv_w, qkv_b, proj_w, proj_b, n2w, n2b,
        fc1_w, fc1_b, fc2_w, fc2_b, wsT, out, fast, wok);
    if (fast)
        swin_scatter<<<dim3(1792), dim3(256), 0, stream>>>(tokW, out);
}

// Round 4
// 747.431 us; speedup vs baseline: 2.3279x; 1.0873x over previous
//
#include <hip/hip_runtime.h>

// ---------------------------------------------------------------------------
// SwinTransformerBlock, MI355X / gfx950. fp32 I/O, bf16 MFMA core.
// wprep -> padfill -> gather -> fused (per 7x7 window) -> scatter.
// This round: LDS 54272->40960 (4 blocks/CU) via register-resident P/O
// (swapped QK^T + cvt_pk_bf16 + ds_bpermute transposes), cheap tanh-GELU.
// ---------------------------------------------------------------------------

typedef __bf16 bf16;
typedef __attribute__((ext_vector_type(8))) __bf16 bf16x8;
typedef __attribute__((ext_vector_type(4))) float f32x4;
typedef __attribute__((ext_vector_type(4))) int i32x4;

#define LDA 104      // row stride (elems) for [64][*] LDS tiles
#define LDV 72       // row stride for V^T [96][*]
#define LDW 233      // gather/scatter transpose-tile stride
#define TOKW 6144    // 64*96 elems per window

union U8 { int i[4]; bf16x8 v; };

__device__ __forceinline__ f32x4 mfma16(bf16x8 a, bf16x8 b, f32x4 c) {
    return __builtin_amdgcn_mfma_f32_16x16x32_bf16(a, b, c, 0, 0, 0);
}
__device__ __forceinline__ int pkbf(float lo, float hi) {
    int r; asm("v_cvt_pk_bf16_f32 %0, %1, %2" : "=v"(r) : "v"(lo), "v"(hi)); return r;
}
__device__ __forceinline__ float rcpf(float x) {
    float r; asm("v_rcp_f32 %0, %1" : "=v"(r) : "v"(x)); return r;
}
__device__ __forceinline__ float gelu_f(float v) {
    // v * sigmoid(2*0.7978845608*(v + 0.044715 v^3)), exp2-based
    const float a = -2.30220770f, b = -0.10294852f;
    float e = exp2f(v * __builtin_fmaf(b, v * v, a));
    return v * rcpf(1.f + e);
}

// ---------------- weight pre-transpose (fp32 -> bf16 [N][K]) ---------------
__global__ void swin_wprep(const float* __restrict__ qkv_w,
                           const float* __restrict__ proj_w,
                           const float* __restrict__ fc1_w,
                           const float* __restrict__ fc2_w,
                           bf16* __restrict__ wsT) {
    int i = blockIdx.x * 256 + threadIdx.x;
    if (i < 27648) { int n = i / 96, k = i - n * 96; wsT[i] = (bf16)qkv_w[k * 288 + n]; }
    else if (i < 36864) { int j = i - 27648, n = j / 96, k = j - n * 96; wsT[i] = (bf16)proj_w[k * 96 + n]; }
    else if (i < 73728) { int j = i - 36864, n = j / 96, k = j - n * 96; wsT[i] = (bf16)fc1_w[k * 384 + n]; }
    else if (i < 110592){ int j = i - 73728, n = j / 384, k = j - n * 384; wsT[i] = (bf16)fc2_w[k * 96 + n]; }
}

// ---------------- K0: zero pad rows 49..63 of every window -----------------
__global__ void swin_padfill(bf16* __restrict__ tokW) {
    int id = blockIdx.x * 256 + threadIdx.x;
    int win = id / 180, r = id - win * 180;
    int row = 49 + r / 12, c8 = r - (r / 12) * 12;
    *(i32x4*)(tokW + (size_t)win * TOKW + row * 96 + c8 * 8) = i32x4{0, 0, 0, 0};
}

// ---------------- K1: x[B,C,H,W] fp32 -> tokW[win][64][96] bf16 ------------
__global__ __launch_bounds__(256)
void swin_gather(const float* __restrict__ x, bf16* __restrict__ tokW) {
    __shared__ bf16 sT[96 * LDW];
    const int tid = threadIdx.x;
    const int bi = blockIdx.x;
    const int b = bi / 224, h = bi - b * 224;
    const int wy = h / 7, ty = h - wy * 7;
    const size_t xbase = (size_t)b * 4816896 + (size_t)h * 224;

#pragma unroll
    for (int i = 0; i < 21; ++i) {
        int id = i * 256 + tid;
        int c = id / 56, w4 = id - c * 56;
        f32x4 v = *(const f32x4*)(x + xbase + (size_t)c * 50176 + w4 * 4);
#pragma unroll
        for (int j = 0; j < 4; ++j) sT[c * LDW + w4 * 4 + j] = (bf16)v[j];
    }
    __syncthreads();

#pragma unroll
    for (int i = 0; i < 11; ++i) {
        int id = i * 256 + tid;
        if (id < 2688) {
            int win = id / 84, r = id - win * 84;
            int tx = r / 12, c8 = r - tx * 12;
            bf16x8 v;
#pragma unroll
            for (int j = 0; j < 8; ++j) v[j] = sT[(c8 * 8 + j) * LDW + win * 7 + tx];
            *(i32x4*)(tokW + (size_t)(b * 1024 + wy * 32 + win) * TOKW
                      + (ty * 7 + tx) * 96 + c8 * 8) = *(i32x4*)&v;
        }
    }
}

// ---------------- K3: tokW -> out[B,C,H,W] fp32 ----------------------------
__global__ __launch_bounds__(256)
void swin_scatter(const bf16* __restrict__ tokW, float* __restrict__ out) {
    __shared__ bf16 sT[96 * LDW];
    const int tid = threadIdx.x;
    const int bi = blockIdx.x;
    const int b = bi / 224, h = bi - b * 224;
    const int wy = h / 7, ty = h - wy * 7;
    const size_t obase = (size_t)b * 4816896 + (size_t)h * 224;

#pragma unroll
    for (int i = 0; i < 11; ++i) {
        int id = i * 256 + tid;
        if (id < 2688) {
            int win = id / 84, r = id - win * 84;
            int tx = r / 12, c8 = r - tx * 12;
            bf16x8 v = *(const bf16x8*)(tokW + (size_t)(b * 1024 + wy * 32 + win) * TOKW
                                        + (ty * 7 + tx) * 96 + c8 * 8);
#pragma unroll
            for (int j = 0; j < 8; ++j) sT[(c8 * 8 + j) * LDW + win * 7 + tx] = v[j];
        }
    }
    __syncthreads();

#pragma unroll
    for (int i = 0; i < 21; ++i) {
        int id = i * 256 + tid;
        int c = id / 56, w4 = id - c * 56;
        f32x4 v;
#pragma unroll
        for (int j = 0; j < 4; ++j) v[j] = (float)sT[c * LDW + w4 * 4 + j];
        *(f32x4*)(out + obase + (size_t)c * 50176 + w4 * 4) = v;
    }
}

__device__ __forceinline__ bf16x8 bload(const bf16* T, const float* worig,
                                        int nrow, int k0, int K, int N, bool wok) {
    if (wok) return *(const bf16x8*)(T + (size_t)nrow * K + k0);
    bf16x8 f;
#pragma unroll
    for (int j = 0; j < 8; ++j) f[j] = (bf16)worig[(size_t)(k0 + j) * N + nrow];
    return f;
}

// ---------------------------- K2: fused block ------------------------------
__global__ __launch_bounds__(256, 4)
void swin_fused(const float* __restrict__ x, bf16* __restrict__ tokW,
                const float* __restrict__ n1w, const float* __restrict__ n1b,
                const float* __restrict__ qkvw, const float* __restrict__ qkvb,
                const float* __restrict__ projw, const float* __restrict__ projb,
                const float* __restrict__ n2w, const float* __restrict__ n2b,
                const float* __restrict__ fc1w, const float* __restrict__ fc1b,
                const float* __restrict__ fc2w, const float* __restrict__ fc2b,
                const bf16* __restrict__ wsT,
                float* __restrict__ out, int fast_i, int wok_i) {
    // 40448 B pool + 512 B stats = 40960 B -> 4 blocks/CU
    __shared__ __attribute__((aligned(16))) bf16 L[20224];
    __shared__ float sStat[128];
    bf16* RB = L;              // raw tokens -> Q -> t2
    bf16* RC = L + 6656;       // K -> hidden chunks
    bf16* RV = L + 13312;      // V^T [96][LDV] -> final output [64][LDA]

    const bool fast = fast_i != 0;
    const bool wok  = wok_i != 0;

    const int tid  = threadIdx.x;
    const int wave = tid >> 6;
    const int lane = tid & 63;
    const int g    = lane >> 4;
    const int q16  = lane & 15;

    const int win = blockIdx.x;
    const int b  = win >> 10;
    const int wy = (win >> 5) & 31;
    const int wx = win & 31;
    const int h0 = wy * 7, w0 = wx * 7;
    const size_t xbase = (size_t)b * 4816896;
    const bf16* myWin = tokW + (size_t)win * TOKW;

    // ---- P0: window -> RB (raw tokens)
    if (fast) {
#pragma unroll
        for (int i = 0; i < 3; ++i) {
            int id = i * 256 + tid;
            int row = id / 12, c8 = id - row * 12;
            *(i32x4*)&RB[row * LDA + c8 * 8] = *(const i32x4*)(myWin + row * 96 + c8 * 8);
        }
    } else {
        for (int i = 0; i < 24; ++i) {
            int id = i * 256 + tid;
            if (id < 4704) {
                int c = id / 49, pix = id - c * 49;
                int ty = pix / 7, tx = pix - ty * 7;
                RB[pix * LDA + c] =
                    (bf16)x[xbase + (size_t)c * 50176 + (h0 + ty) * 224 + w0 + tx];
            } else if (id < 6144) {
                int j = id - 4704;
                int row = 49 + j / 96, c = j - (j / 96) * 96;
                RB[row * LDA + c] = (bf16)0.f;
            }
        }
    }
    __syncthreads();

    // ---- LN1 stats
    {
        int r = tid >> 2, p = tid & 3;
        float s = 0.f, s2 = 0.f;
#pragma unroll
        for (int v8 = 0; v8 < 3; ++v8) {
            bf16x8 v = *(const bf16x8*)&RB[r * LDA + p * 24 + v8 * 8];
#pragma unroll
            for (int j = 0; j < 8; ++j) { float f = (float)v[j]; s += f; s2 += f * f; }
        }
        s += __shfl_xor(s, 1);  s2 += __shfl_xor(s2, 1);
        s += __shfl_xor(s, 2);  s2 += __shfl_xor(s2, 2);
        if (p == 0) {
            float mu  = s * (1.f / 96.f);
            float var = s2 * (1.f / 96.f) - mu * mu;
            sStat[r]      = mu;
            sStat[64 + r] = rsqrtf(fmaxf(var, 0.f) + 1e-5f);
        }
    }
    __syncthreads();

    // ---- LN1'd A-frags in regs (raw read from RB before Q overwrites it)
    bf16x8 afrag[3][4];
#pragma unroll
    for (int s = 0; s < 3; ++s) {
        const int c0 = s * 32 + g * 8;
        float wv[8], bv[8];
#pragma unroll
        for (int j = 0; j < 8; ++j) { wv[j] = n1w[c0 + j]; bv[j] = n1b[c0 + j]; }
#pragma unroll
        for (int m = 0; m < 4; ++m) {
            int row = m * 16 + q16;
            float mu = sStat[row], rs = sStat[64 + row];
            bf16x8 raw = *(const bf16x8*)&RB[row * LDA + c0];
            bf16x8 f;
#pragma unroll
            for (int j = 0; j < 8; ++j)
                f[j] = (bf16)(((float)raw[j] - mu) * rs * wv[j] + bv[j]);
            afrag[s][m] = f;
        }
    }
    __syncthreads();   // all raw reads done; RB reusable for Q

    const bf16* qkvT  = wsT;
    const bf16* projT = wsT + 27648;
    const bf16* fc1T  = wsT + 36864;
    const bf16* fc2T  = wsT + 73728;

    // ---- QKV GEMM (N-split across waves)
    for (int nt = wave; nt < 18; nt += 4) {
        const int nrow = nt * 16 + q16;
        f32x4 acc[4] = {{0,0,0,0},{0,0,0,0},{0,0,0,0},{0,0,0,0}};
#pragma unroll
        for (int s = 0; s < 3; ++s) {
            bf16x8 bf = bload(qkvT, qkvw, nrow, s * 32 + g * 8, 96, 288, wok);
#pragma unroll
            for (int m = 0; m < 4; ++m) acc[m] = mfma16(afrag[s][m], bf, acc[m]);
        }
        float bias = qkvb[nrow];
#pragma unroll
        for (int m = 0; m < 4; ++m)
#pragma unroll
            for (int r = 0; r < 4; ++r) {
                float v = acc[m][r] + bias;
                int row = m * 16 + g * 4 + r;
                bf16 hv = (bf16)v;
                if (nrow < 96)        RB[row * LDA + nrow] = hv;              // Q
                else if (nrow < 192)  RC[row * LDA + (nrow - 96)] = hv;       // K
                else                  RV[(nrow - 192) * LDV + row] = hv;      // V^T
            }
    }
    __syncthreads();   // Q/K/V ready

    // ---- attention: swapped QK^T; P and O stay in registers.
    // Lane (g,q16) of wave w owns query q = w*16+q16 (cols of D).
    const float sc_l2e = 0.17677669529663688f * 1.4426950408889634f;
    const bool hi5 = (lane & 32) != 0;
    const int addr0 = ((lane & 16) << 3) | (q16 << 2);  // 4*(q16 + (g&1)*32)
    const int addr1 = addr0 + 64;                       // + 16 lanes
    f32x4 oacc[3][2];
#pragma unroll
    for (int h = 0; h < 3; ++h) {
        bf16x8 bq = *(const bf16x8*)&RB[(wave * 16 + q16) * LDA + h * 32 + g * 8];
        f32x4 s4s[4];
#pragma unroll
        for (int kt = 0; kt < 4; ++kt) {
            bf16x8 ak = *(const bf16x8*)&RC[(kt * 16 + q16) * LDA + h * 32 + g * 8];
            f32x4 z = {0, 0, 0, 0};
            s4s[kt] = mfma16(ak, bq, z);   // S^T[key=kt*16+g*4+r][q=q16]
        }
        // softmax over the 16 in-lane keys + cross-g reduce (keys 49..63 masked)
        float m0 = -1e30f;
#pragma unroll
        for (int kt = 0; kt < 3; ++kt)
#pragma unroll
            for (int r = 0; r < 4; ++r) m0 = fmaxf(m0, s4s[kt][r]);
        m0 = fmaxf(m0, (g == 0) ? s4s[3][0] : -1e30f);
        m0 = fmaxf(m0, __shfl_xor(m0, 16));
        m0 = fmaxf(m0, __shfl_xor(m0, 32));
        float ss = 0.f;
#pragma unroll
        for (int kt = 0; kt < 3; ++kt)
#pragma unroll
            for (int r = 0; r < 4; ++r) {
                float e = exp2f((s4s[kt][r] - m0) * sc_l2e);
                s4s[kt][r] = e; ss += e;
            }
        {
            float e = (g == 0) ? exp2f((s4s[3][0] - m0) * sc_l2e) : 0.f;
            s4s[3][0] = e; ss += e;
            s4s[3][1] = 0.f; s4s[3][2] = 0.f; s4s[3][3] = 0.f;
        }
        ss += __shfl_xor(ss, 16);
        ss += __shfl_xor(ss, 32);
        float inv = rcpf(ss);

        // P (C-layout regs) -> PV B-frags via cvt_pk + ds_bpermute
        int u[4][2];
#pragma unroll
        for (int kt = 0; kt < 4; ++kt) {
            u[kt][0] = pkbf(s4s[kt][0], s4s[kt][1]);
            u[kt][1] = pkbf(s4s[kt][2], s4s[kt][3]);
        }
        bf16x8 ap[2];
#pragma unroll
        for (int kh = 0; kh < 2; ++kh) {
            U8 w;
            int a0 = __builtin_amdgcn_ds_bpermute(addr0, u[kh * 2][0]);
            int b0 = __builtin_amdgcn_ds_bpermute(addr0, u[kh * 2 + 1][0]);
            w.i[0] = hi5 ? b0 : a0;
            int a1 = __builtin_amdgcn_ds_bpermute(addr0, u[kh * 2][1]);
            int b1 = __builtin_amdgcn_ds_bpermute(addr0, u[kh * 2 + 1][1]);
            w.i[1] = hi5 ? b1 : a1;
            int a2 = __builtin_amdgcn_ds_bpermute(addr1, u[kh * 2][0]);
            int b2 = __builtin_amdgcn_ds_bpermute(addr1, u[kh * 2 + 1][0]);
            w.i[2] = hi5 ? b2 : a2;
            int a3 = __builtin_amdgcn_ds_bpermute(addr1, u[kh * 2][1]);
            int b3 = __builtin_amdgcn_ds_bpermute(addr1, u[kh * 2 + 1][1]);
            w.i[3] = hi5 ? b3 : a3;
            ap[kh] = w.v;
        }
        // O^T[d][q] = V^T x P
#pragma unroll
        for (int n2 = 0; n2 < 2; ++n2) {
            int d0 = (h * 32 + n2 * 16 + q16) * LDV;
            f32x4 oa = {0, 0, 0, 0};
            oa = mfma16(*(const bf16x8*)&RV[d0 + g * 8], ap[0], oa);
            oa = mfma16(*(const bf16x8*)&RV[d0 + 32 + g * 8], ap[1], oa);
#pragma unroll
            for (int r = 0; r < 4; ++r) oa[r] *= inv;
            oacc[h][n2] = oa;
        }
    }

    // ---- proj (M-split: wave owns its 16 tokens); A-frags from oacc regs
    int u2[3][2][2];
#pragma unroll
    for (int h = 0; h < 3; ++h)
#pragma unroll
        for (int n2 = 0; n2 < 2; ++n2) {
            u2[h][n2][0] = pkbf(oacc[h][n2][0], oacc[h][n2][1]);
            u2[h][n2][1] = pkbf(oacc[h][n2][2], oacc[h][n2][3]);
        }
    bf16x8 aoM[3];
#pragma unroll
    for (int s = 0; s < 3; ++s) {
        U8 w;
        int a0 = __builtin_amdgcn_ds_bpermute(addr0, u2[s][0][0]);
        int b0 = __builtin_amdgcn_ds_bpermute(addr0, u2[s][1][0]);
        w.i[0] = hi5 ? b0 : a0;
        int a1 = __builtin_amdgcn_ds_bpermute(addr0, u2[s][0][1]);
        int b1 = __builtin_amdgcn_ds_bpermute(addr0, u2[s][1][1]);
        w.i[1] = hi5 ? b1 : a1;
        int a2 = __builtin_amdgcn_ds_bpermute(addr1, u2[s][0][0]);
        int b2 = __builtin_amdgcn_ds_bpermute(addr1, u2[s][1][0]);
        w.i[2] = hi5 ? b2 : a2;
        int a3 = __builtin_amdgcn_ds_bpermute(addr1, u2[s][0][1]);
        int b3 = __builtin_amdgcn_ds_bpermute(addr1, u2[s][1][1]);
        w.i[3] = hi5 ? b3 : a3;
        aoM[s] = w.v;
    }
    {
        f32x4 pacc[6] = {{0,0,0,0},{0,0,0,0},{0,0,0,0},{0,0,0,0},{0,0,0,0},{0,0,0,0}};
#pragma unroll
        for (int nt = 0; nt < 6; ++nt) {
            int nrow = nt * 16 + q16;
#pragma unroll
            for (int s = 0; s < 3; ++s) {
                bf16x8 bf = bload(projT, projw, nrow, s * 32 + g * 8, 96, 96, wok);
                pacc[nt] = mfma16(aoM[s], bf, pacc[nt]);
            }
        }
#pragma unroll
        for (int nt = 0; nt < 6; ++nt) {
            int nrow = nt * 16 + q16;
            float bias = projb[nrow];
#pragma unroll
            for (int r = 0; r < 4; ++r) {
                int row = wave * 16 + g * 4 + r;
                float sc;
                if (fast) sc = (float)myWin[row * 96 + nrow];
                else      sc = (row < 49)
                    ? x[xbase + (size_t)nrow * 50176 + (h0 + row / 7) * 224 + w0 + row % 7]
                    : 0.f;
                RB[row * LDA + nrow] = (bf16)(pacc[nt][r] + bias + sc);   // t2
            }
        }
    }
    __syncthreads();

    // ---- LN2 stats (t2 in RB)
    {
        int r = tid >> 2, p = tid & 3;
        float s = 0.f, s2 = 0.f;
#pragma unroll
        for (int v8 = 0; v8 < 3; ++v8) {
            bf16x8 v = *(const bf16x8*)&RB[r * LDA + p * 24 + v8 * 8];
#pragma unroll
            for (int j = 0; j < 8; ++j) { float f = (float)v[j]; s += f; s2 += f * f; }
        }
        s += __shfl_xor(s, 1);  s2 += __shfl_xor(s2, 1);
        s += __shfl_xor(s, 2);  s2 += __shfl_xor(s2, 2);
        if (p == 0) {
            float mu  = s * (1.f / 96.f);
            float var = s2 * (1.f / 96.f) - mu * mu;
            sStat[r]      = mu;
            sStat[64 + r] = rsqrtf(fmaxf(var, 0.f) + 1e-5f);
        }
    }
    __syncthreads();

    // ---- MLP: LN2'd A-frags held across chunks
    bf16x8 am[3][4];
#pragma unroll
    for (int s = 0; s < 3; ++s) {
        const int c0 = s * 32 + g * 8;
        float wv[8], bv[8];
#pragma unroll
        for (int j = 0; j < 8; ++j) { wv[j] = n2w[c0 + j]; bv[j] = n2b[c0 + j]; }
#pragma unroll
        for (int m = 0; m < 4; ++m) {
            int row = m * 16 + q16;
            float mu = sStat[row], rs = sStat[64 + row];
            bf16x8 raw = *(const bf16x8*)&RB[row * LDA + c0];
            bf16x8 f;
#pragma unroll
            for (int j = 0; j < 8; ++j)
                f[j] = (bf16)(((float)raw[j] - mu) * rs * wv[j] + bv[j]);
            am[s][m] = f;
        }
    }

    const int npt = (wave < 2) ? 2 : 1;
    f32x4 f2acc[2][4] = {{{0,0,0,0},{0,0,0,0},{0,0,0,0},{0,0,0,0}},
                         {{0,0,0,0},{0,0,0,0},{0,0,0,0},{0,0,0,0}}};
    for (int ch = 0; ch < 4; ++ch) {
#pragma unroll
        for (int t = 0; t < 2; ++t) {
            if (t < npt) {
                int ntl = (t == 0) ? wave : wave + 4;
                int nrow = (ch * 6 + ntl) * 16 + q16;
                f32x4 acc[4] = {{0,0,0,0},{0,0,0,0},{0,0,0,0},{0,0,0,0}};
#pragma unroll
                for (int s = 0; s < 3; ++s) {
                    bf16x8 bf = bload(fc1T, fc1w, nrow, s * 32 + g * 8, 96, 384, wok);
#pragma unroll
                    for (int m = 0; m < 4; ++m) acc[m] = mfma16(am[s][m], bf, acc[m]);
                }
                float bias = fc1b[nrow];
#pragma unroll
                for (int m = 0; m < 4; ++m)
#pragma unroll
                    for (int r = 0; r < 4; ++r)
                        RC[(m * 16 + g * 4 + r) * LDA + ntl * 16 + q16] =
                            (bf16)gelu_f(acc[m][r] + bias);
            }
        }
        __syncthreads();
        bf16x8 ah[3][4];
#pragma unroll
        for (int s = 0; s < 3; ++s)
#pragma unroll
            for (int m = 0; m < 4; ++m)
                ah[s][m] = *(const bf16x8*)&RC[(m * 16 + q16) * LDA + s * 32 + g * 8];
#pragma unroll
        for (int t = 0; t < 2; ++t) {
            if (t < npt) {
                int nt = (t == 0) ? wave : wave + 4;
                int nrow = nt * 16 + q16;
#pragma unroll
                for (int s = 0; s < 3; ++s) {
                    bf16x8 bf = bload(fc2T, fc2w, nrow, ch * 96 + s * 32 + g * 8, 384, 96, wok);
#pragma unroll
                    for (int m = 0; m < 4; ++m) f2acc[t][m] = mfma16(ah[s][m], bf, f2acc[t][m]);
                }
            }
        }
        __syncthreads();
    }

    // ---- final: out = t2 + fc2 + bias -> RV as [64][LDA]
#pragma unroll
    for (int t = 0; t < 2; ++t) {
        if (t < npt) {
            int col = ((t == 0) ? wave : wave + 4) * 16 + q16;
            float bias = fc2b[col];
#pragma unroll
            for (int m = 0; m < 4; ++m)
#pragma unroll
                for (int r = 0; r < 4; ++r) {
                    int row = m * 16 + g * 4 + r;
                    float t2 = (float)RB[row * LDA + col];
                    RV[row * LDA + col] = (bf16)(f2acc[t][m][r] + bias + t2);
                }
        }
    }
    __syncthreads();

    // ---- store (rows 0..48)
    if (fast) {
#pragma unroll
        for (int i = 0; i < 3; ++i) {
            int id = i * 256 + tid;
            if (id < 588) {
                int row = id / 12, c8 = id - row * 12;
                *(i32x4*)(tokW + (size_t)win * TOKW + row * 96 + c8 * 8) =
                    *(const i32x4*)&RV[row * LDA + c8 * 8];
            }
        }
    } else {
        for (int i = 0; i < 19; ++i) {
            int id = i * 256 + tid;
            if (id < 4704) {
                int c = id / 49, pix = id - c * 49;
                int ty = pix / 7, tx = pix - ty * 7;
                out[xbase + (size_t)c * 50176 + (h0 + ty) * 224 + w0 + tx] =
                    (float)RV[pix * LDA + c];
            }
        }
    }
}

// ---------------------------------------------------------------------------
extern "C" void kernel_launch(void* const* d_in, const int* in_sizes, int n_in,
                              void* d_out, int out_size, void* d_ws, size_t ws_size,
                              hipStream_t stream) {
    const float* x      = (const float*)d_in[0];
    const float* n1w    = (const float*)d_in[1];
    const float* n1b    = (const float*)d_in[2];
    const float* qkv_w  = (const float*)d_in[3];
    const float* qkv_b  = (const float*)d_in[4];
    const float* proj_w = (const float*)d_in[5];
    const float* proj_b = (const float*)d_in[6];
    const float* n2w    = (const float*)d_in[7];
    const float* n2b    = (const float*)d_in[8];
    const float* fc1_w  = (const float*)d_in[9];
    const float* fc1_b  = (const float*)d_in[10];
    const float* fc2_w  = (const float*)d_in[11];
    const float* fc2_b  = (const float*)d_in[12];
    float* out = (float*)d_out;

    const size_t TOKW_OFF = 225280;
    const int wok  = (ws_size >= 221184) ? 1 : 0;
    const int fast = (ws_size >= TOKW_OFF + 100663296ull) ? 1 : 0;
    bf16* wsT  = (bf16*)d_ws;
    bf16* tokW = (bf16*)((char*)d_ws + TOKW_OFF);

    if (wok)
        swin_wprep<<<dim3(432), dim3(256), 0, stream>>>(qkv_w, proj_w, fc1_w, fc2_w, wsT);
    if (fast) {
        swin_padfill<<<dim3(5760), dim3(256), 0, stream>>>(tokW);
        swin_gather<<<dim3(1792), dim3(256), 0, stream>>>(x, tokW);
    }
    swin_fused<<<dim3(8192), dim3(256), 0, stream>>>(
        x, tokW, n1w, n1b, qkv_w, qkv_b, proj_w, proj_b, n2w, n2b,
        fc1_w, fc1_b, fc2_w, fc2_b, wsT, out, fast, wok);
    if (fast)
        swin_scatter<<<dim3(1792), dim3(256), 0, stream>>>(tokW, out);
}

// Round 5
// 444.501 us; speedup vs baseline: 3.9143x; 1.6815x over previous
//
#include <hip/hip_runtime.h>

// ---------------------------------------------------------------------------
// SwinTransformerBlock, MI355X / gfx950. fp32 I/O, bf16 MFMA core.
// wprep -> padfill -> gather -> fused (per 7x7 window) -> scatter.
// Round 5: eliminate scratch spills (VGPR peak ~100 < 128 @ 4 blocks/CU):
//   - LN stats+normalize fused in place in LDS (no reg-held A-frag arrays)
//   - raw t2 parked in dead V^T LDS region
//   - fc1/fc2 stream A-frags per k-step (32-reg window)
// ---------------------------------------------------------------------------

typedef __bf16 bf16;
typedef __attribute__((ext_vector_type(8))) __bf16 bf16x8;
typedef __attribute__((ext_vector_type(4))) float f32x4;
typedef __attribute__((ext_vector_type(4))) int i32x4;

#define LDA 104      // row stride (elems) for [64][*] LDS tiles
#define LDV 72       // row stride for V^T [96][*]
#define LDW 233      // gather/scatter transpose-tile stride
#define TOKW 6144    // 64*96 elems per window

union U8 { int i[4]; bf16x8 v; };

__device__ __forceinline__ f32x4 mfma16(bf16x8 a, bf16x8 b, f32x4 c) {
    return __builtin_amdgcn_mfma_f32_16x16x32_bf16(a, b, c, 0, 0, 0);
}
__device__ __forceinline__ int pkbf(float lo, float hi) {
    int r; asm("v_cvt_pk_bf16_f32 %0, %1, %2" : "=v"(r) : "v"(lo), "v"(hi)); return r;
}
__device__ __forceinline__ float rcpf(float x) {
    float r; asm("v_rcp_f32 %0, %1" : "=v"(r) : "v"(x)); return r;
}
__device__ __forceinline__ float gelu_f(float v) {
    const float a = -2.30220770f, b = -0.10294852f;
    float e = exp2f(v * __builtin_fmaf(b, v * v, a));
    return v * rcpf(1.f + e);
}

// ---------------- weight pre-transpose (fp32 -> bf16 [N][K]) ---------------
__global__ void swin_wprep(const float* __restrict__ qkv_w,
                           const float* __restrict__ proj_w,
                           const float* __restrict__ fc1_w,
                           const float* __restrict__ fc2_w,
                           bf16* __restrict__ wsT) {
    int i = blockIdx.x * 256 + threadIdx.x;
    if (i < 27648) { int n = i / 96, k = i - n * 96; wsT[i] = (bf16)qkv_w[k * 288 + n]; }
    else if (i < 36864) { int j = i - 27648, n = j / 96, k = j - n * 96; wsT[i] = (bf16)proj_w[k * 96 + n]; }
    else if (i < 73728) { int j = i - 36864, n = j / 96, k = j - n * 96; wsT[i] = (bf16)fc1_w[k * 384 + n]; }
    else if (i < 110592){ int j = i - 73728, n = j / 384, k = j - n * 384; wsT[i] = (bf16)fc2_w[k * 96 + n]; }
}

// ---------------- K0: zero pad rows 49..63 of every window -----------------
__global__ void swin_padfill(bf16* __restrict__ tokW) {
    int id = blockIdx.x * 256 + threadIdx.x;
    int win = id / 180, r = id - win * 180;
    int row = 49 + r / 12, c8 = r - (r / 12) * 12;
    *(i32x4*)(tokW + (size_t)win * TOKW + row * 96 + c8 * 8) = i32x4{0, 0, 0, 0};
}

// ---------------- K1: x[B,C,H,W] fp32 -> tokW[win][64][96] bf16 ------------
__global__ __launch_bounds__(256)
void swin_gather(const float* __restrict__ x, bf16* __restrict__ tokW) {
    __shared__ bf16 sT[96 * LDW];
    const int tid = threadIdx.x;
    const int bi = blockIdx.x;
    const int b = bi / 224, h = bi - b * 224;
    const int wy = h / 7, ty = h - wy * 7;
    const size_t xbase = (size_t)b * 4816896 + (size_t)h * 224;

#pragma unroll
    for (int i = 0; i < 21; ++i) {
        int id = i * 256 + tid;
        int c = id / 56, w4 = id - c * 56;
        f32x4 v = *(const f32x4*)(x + xbase + (size_t)c * 50176 + w4 * 4);
#pragma unroll
        for (int j = 0; j < 4; ++j) sT[c * LDW + w4 * 4 + j] = (bf16)v[j];
    }
    __syncthreads();

#pragma unroll
    for (int i = 0; i < 11; ++i) {
        int id = i * 256 + tid;
        if (id < 2688) {
            int win = id / 84, r = id - win * 84;
            int tx = r / 12, c8 = r - tx * 12;
            bf16x8 v;
#pragma unroll
            for (int j = 0; j < 8; ++j) v[j] = sT[(c8 * 8 + j) * LDW + win * 7 + tx];
            *(i32x4*)(tokW + (size_t)(b * 1024 + wy * 32 + win) * TOKW
                      + (ty * 7 + tx) * 96 + c8 * 8) = *(i32x4*)&v;
        }
    }
}

// ---------------- K3: tokW -> out[B,C,H,W] fp32 ----------------------------
__global__ __launch_bounds__(256)
void swin_scatter(const bf16* __restrict__ tokW, float* __restrict__ out) {
    __shared__ bf16 sT[96 * LDW];
    const int tid = threadIdx.x;
    const int bi = blockIdx.x;
    const int b = bi / 224, h = bi - b * 224;
    const int wy = h / 7, ty = h - wy * 7;
    const size_t obase = (size_t)b * 4816896 + (size_t)h * 224;

#pragma unroll
    for (int i = 0; i < 11; ++i) {
        int id = i * 256 + tid;
        if (id < 2688) {
            int win = id / 84, r = id - win * 84;
            int tx = r / 12, c8 = r - tx * 12;
            bf16x8 v = *(const bf16x8*)(tokW + (size_t)(b * 1024 + wy * 32 + win) * TOKW
                                        + (ty * 7 + tx) * 96 + c8 * 8);
#pragma unroll
            for (int j = 0; j < 8; ++j) sT[(c8 * 8 + j) * LDW + win * 7 + tx] = v[j];
        }
    }
    __syncthreads();

#pragma unroll
    for (int i = 0; i < 21; ++i) {
        int id = i * 256 + tid;
        int c = id / 56, w4 = id - c * 56;
        f32x4 v;
#pragma unroll
        for (int j = 0; j < 4; ++j) v[j] = (float)sT[c * LDW + w4 * 4 + j];
        *(f32x4*)(out + obase + (size_t)c * 50176 + w4 * 4) = v;
    }
}

__device__ __forceinline__ bf16x8 bload(const bf16* T, const float* worig,
                                        int nrow, int k0, int K, int N, bool wok) {
    if (wok) return *(const bf16x8*)(T + (size_t)nrow * K + k0);
    bf16x8 f;
#pragma unroll
    for (int j = 0; j < 8; ++j) f[j] = (bf16)worig[(size_t)(k0 + j) * N + nrow];
    return f;
}

// ---------------------------- K2: fused block ------------------------------
__global__ __launch_bounds__(256, 4)
void swin_fused(const float* __restrict__ x, bf16* __restrict__ tokW,
                const float* __restrict__ n1w, const float* __restrict__ n1b,
                const float* __restrict__ qkvw, const float* __restrict__ qkvb,
                const float* __restrict__ projw, const float* __restrict__ projb,
                const float* __restrict__ n2w, const float* __restrict__ n2b,
                const float* __restrict__ fc1w, const float* __restrict__ fc1b,
                const float* __restrict__ fc2w, const float* __restrict__ fc2b,
                const bf16* __restrict__ wsT,
                float* __restrict__ out, int fast_i, int wok_i) {
    // 40448 B -> 4 blocks/CU
    __shared__ __attribute__((aligned(16))) bf16 L[20224];
    bf16* RB = L;              // raw -> LN1'd -> Q -> LN2'd t2
    bf16* RC = L + 6656;       // K -> hidden chunks
    bf16* RV = L + 13312;      // V^T [96][LDV] -> raw t2 [64][LDA] -> output

    const bool fast = fast_i != 0;
    const bool wok  = wok_i != 0;

    const int tid  = threadIdx.x;
    const int wave = tid >> 6;
    const int lane = tid & 63;
    const int g    = lane >> 4;
    const int q16  = lane & 15;

    const int win = blockIdx.x;
    const int b  = win >> 10;
    const int wy = (win >> 5) & 31;
    const int wx = win & 31;
    const int h0 = wy * 7, w0 = wx * 7;
    const size_t xbase = (size_t)b * 4816896;
    const bf16* myWin = tokW + (size_t)win * TOKW;

    // ---- P0: window -> RB (raw tokens)
    if (fast) {
#pragma unroll
        for (int i = 0; i < 3; ++i) {
            int id = i * 256 + tid;
            int row = id / 12, c8 = id - row * 12;
            *(i32x4*)&RB[row * LDA + c8 * 8] = *(const i32x4*)(myWin + row * 96 + c8 * 8);
        }
    } else {
        for (int i = 0; i < 24; ++i) {
            int id = i * 256 + tid;
            if (id < 4704) {
                int c = id / 49, pix = id - c * 49;
                int ty = pix / 7, tx = pix - ty * 7;
                RB[pix * LDA + c] =
                    (bf16)x[xbase + (size_t)c * 50176 + (h0 + ty) * 224 + w0 + tx];
            } else if (id < 6144) {
                int j = id - 4704;
                int row = 49 + j / 96, c = j - (j / 96) * 96;
                RB[row * LDA + c] = (bf16)0.f;
            }
        }
    }
    __syncthreads();

    // ---- LN1: stats + normalize in place (4 lanes per row)
    {
        int r = tid >> 2, p = tid & 3;
        const int c0 = p * 24;
        bf16* rp = &RB[r * LDA + c0];
        bf16x8 v0 = *(const bf16x8*)rp;
        bf16x8 v1 = *(const bf16x8*)(rp + 8);
        bf16x8 v2 = *(const bf16x8*)(rp + 16);
        float s = 0.f, s2 = 0.f;
#pragma unroll
        for (int j = 0; j < 8; ++j) {
            float a = (float)v0[j], c = (float)v1[j], d = (float)v2[j];
            s += a + c + d; s2 += a * a + c * c + d * d;
        }
        s += __shfl_xor(s, 1);  s2 += __shfl_xor(s2, 1);
        s += __shfl_xor(s, 2);  s2 += __shfl_xor(s2, 2);
        float mu = s * (1.f / 96.f);
        float rs = rsqrtf(fmaxf(s2 * (1.f / 96.f) - mu * mu, 0.f) + 1e-5f);
        bf16x8 o0, o1, o2;
#pragma unroll
        for (int j = 0; j < 8; ++j) {
            o0[j] = (bf16)(((float)v0[j] - mu) * rs * n1w[c0 + j] + n1b[c0 + j]);
            o1[j] = (bf16)(((float)v1[j] - mu) * rs * n1w[c0 + 8 + j] + n1b[c0 + 8 + j]);
            o2[j] = (bf16)(((float)v2[j] - mu) * rs * n1w[c0 + 16 + j] + n1b[c0 + 16 + j]);
        }
        *(bf16x8*)rp = o0; *(bf16x8*)(rp + 8) = o1; *(bf16x8*)(rp + 16) = o2;
    }
    __syncthreads();

    // ---- A-frags for QKV from LN1'd RB (held only through QKV phase)
    bf16x8 afrag[3][4];
#pragma unroll
    for (int s = 0; s < 3; ++s)
#pragma unroll
        for (int m = 0; m < 4; ++m)
            afrag[s][m] = *(const bf16x8*)&RB[(m * 16 + q16) * LDA + s * 32 + g * 8];
    __syncthreads();   // all LN1'd reads done; RB reusable for Q

    const bf16* qkvT  = wsT;
    const bf16* projT = wsT + 27648;
    const bf16* fc1T  = wsT + 36864;
    const bf16* fc2T  = wsT + 73728;

    // ---- QKV GEMM (N-split across waves)
    for (int nt = wave; nt < 18; nt += 4) {
        const int nrow = nt * 16 + q16;
        f32x4 acc[4] = {{0,0,0,0},{0,0,0,0},{0,0,0,0},{0,0,0,0}};
#pragma unroll
        for (int s = 0; s < 3; ++s) {
            bf16x8 bf = bload(qkvT, qkvw, nrow, s * 32 + g * 8, 96, 288, wok);
#pragma unroll
            for (int m = 0; m < 4; ++m) acc[m] = mfma16(afrag[s][m], bf, acc[m]);
        }
        float bias = qkvb[nrow];
#pragma unroll
        for (int m = 0; m < 4; ++m)
#pragma unroll
            for (int r = 0; r < 4; ++r) {
                float v = acc[m][r] + bias;
                int row = m * 16 + g * 4 + r;
                bf16 hv = (bf16)v;
                if (nrow < 96)        RB[row * LDA + nrow] = hv;              // Q
                else if (nrow < 192)  RC[row * LDA + (nrow - 96)] = hv;       // K
                else                  RV[(nrow - 192) * LDV + row] = hv;      // V^T
            }
    }
    __syncthreads();   // Q/K/V ready

    // ---- attention: swapped QK^T; P and O in registers
    const float sc_l2e = 0.17677669529663688f * 1.4426950408889634f;
    const bool hi5 = (lane & 32) != 0;
    const int addr0 = ((lane & 16) << 3) | (q16 << 2);
    const int addr1 = addr0 + 64;
    f32x4 oacc[3][2];
#pragma unroll
    for (int h = 0; h < 3; ++h) {
        bf16x8 bq = *(const bf16x8*)&RB[(wave * 16 + q16) * LDA + h * 32 + g * 8];
        f32x4 s4s[4];
#pragma unroll
        for (int kt = 0; kt < 4; ++kt) {
            bf16x8 ak = *(const bf16x8*)&RC[(kt * 16 + q16) * LDA + h * 32 + g * 8];
            f32x4 z = {0, 0, 0, 0};
            s4s[kt] = mfma16(ak, bq, z);   // S^T[key=kt*16+g*4+r][q=q16]
        }
        float m0 = -1e30f;
#pragma unroll
        for (int kt = 0; kt < 3; ++kt)
#pragma unroll
            for (int r = 0; r < 4; ++r) m0 = fmaxf(m0, s4s[kt][r]);
        m0 = fmaxf(m0, (g == 0) ? s4s[3][0] : -1e30f);
        m0 = fmaxf(m0, __shfl_xor(m0, 16));
        m0 = fmaxf(m0, __shfl_xor(m0, 32));
        float ss = 0.f;
#pragma unroll
        for (int kt = 0; kt < 3; ++kt)
#pragma unroll
            for (int r = 0; r < 4; ++r) {
                float e = exp2f((s4s[kt][r] - m0) * sc_l2e);
                s4s[kt][r] = e; ss += e;
            }
        {
            float e = (g == 0) ? exp2f((s4s[3][0] - m0) * sc_l2e) : 0.f;
            s4s[3][0] = e; ss += e;
            s4s[3][1] = 0.f; s4s[3][2] = 0.f; s4s[3][3] = 0.f;
        }
        ss += __shfl_xor(ss, 16);
        ss += __shfl_xor(ss, 32);
        float inv = rcpf(ss);

        int u[4][2];
#pragma unroll
        for (int kt = 0; kt < 4; ++kt) {
            u[kt][0] = pkbf(s4s[kt][0], s4s[kt][1]);
            u[kt][1] = pkbf(s4s[kt][2], s4s[kt][3]);
        }
        bf16x8 ap[2];
#pragma unroll
        for (int kh = 0; kh < 2; ++kh) {
            U8 w;
            int a0 = __builtin_amdgcn_ds_bpermute(addr0, u[kh * 2][0]);
            int b0 = __builtin_amdgcn_ds_bpermute(addr0, u[kh * 2 + 1][0]);
            w.i[0] = hi5 ? b0 : a0;
            int a1 = __builtin_amdgcn_ds_bpermute(addr0, u[kh * 2][1]);
            int b1 = __builtin_amdgcn_ds_bpermute(addr0, u[kh * 2 + 1][1]);
            w.i[1] = hi5 ? b1 : a1;
            int a2 = __builtin_amdgcn_ds_bpermute(addr1, u[kh * 2][0]);
            int b2 = __builtin_amdgcn_ds_bpermute(addr1, u[kh * 2 + 1][0]);
            w.i[2] = hi5 ? b2 : a2;
            int a3 = __builtin_amdgcn_ds_bpermute(addr1, u[kh * 2][1]);
            int b3 = __builtin_amdgcn_ds_bpermute(addr1, u[kh * 2 + 1][1]);
            w.i[3] = hi5 ? b3 : a3;
            ap[kh] = w.v;
        }
#pragma unroll
        for (int n2 = 0; n2 < 2; ++n2) {
            int d0 = (h * 32 + n2 * 16 + q16) * LDV;
            f32x4 oa = {0, 0, 0, 0};
            oa = mfma16(*(const bf16x8*)&RV[d0 + g * 8], ap[0], oa);
            oa = mfma16(*(const bf16x8*)&RV[d0 + 32 + g * 8], ap[1], oa);
#pragma unroll
            for (int r = 0; r < 4; ++r) oa[r] *= inv;
            oacc[h][n2] = oa;
        }
    }
    __syncthreads();   // all V^T reads done; RV reusable for raw t2

    // ---- proj (M-split); A-frags from oacc via cvt_pk + bpermute
    {
        int u2[3][2][2];
#pragma unroll
        for (int h = 0; h < 3; ++h)
#pragma unroll
            for (int n2 = 0; n2 < 2; ++n2) {
                u2[h][n2][0] = pkbf(oacc[h][n2][0], oacc[h][n2][1]);
                u2[h][n2][1] = pkbf(oacc[h][n2][2], oacc[h][n2][3]);
            }
        bf16x8 aoM[3];
#pragma unroll
        for (int s = 0; s < 3; ++s) {
            U8 w;
            int a0 = __builtin_amdgcn_ds_bpermute(addr0, u2[s][0][0]);
            int b0 = __builtin_amdgcn_ds_bpermute(addr0, u2[s][1][0]);
            w.i[0] = hi5 ? b0 : a0;
            int a1 = __builtin_amdgcn_ds_bpermute(addr0, u2[s][0][1]);
            int b1 = __builtin_amdgcn_ds_bpermute(addr0, u2[s][1][1]);
            w.i[1] = hi5 ? b1 : a1;
            int a2 = __builtin_amdgcn_ds_bpermute(addr1, u2[s][0][0]);
            int b2 = __builtin_amdgcn_ds_bpermute(addr1, u2[s][1][0]);
            w.i[2] = hi5 ? b2 : a2;
            int a3 = __builtin_amdgcn_ds_bpermute(addr1, u2[s][0][1]);
            int b3 = __builtin_amdgcn_ds_bpermute(addr1, u2[s][1][1]);
            w.i[3] = hi5 ? b3 : a3;
            aoM[s] = w.v;
        }
#pragma unroll
        for (int nt = 0; nt < 6; ++nt) {
            int nrow = nt * 16 + q16;
            f32x4 pacc = {0, 0, 0, 0};
#pragma unroll
            for (int s = 0; s < 3; ++s) {
                bf16x8 bf = bload(projT, projw, nrow, s * 32 + g * 8, 96, 96, wok);
                pacc = mfma16(aoM[s], bf, pacc);
            }
            float bias = projb[nrow];
#pragma unroll
            for (int r = 0; r < 4; ++r) {
                int row = wave * 16 + g * 4 + r;
                float sc;
                if (fast) sc = (float)myWin[row * 96 + nrow];
                else      sc = (row < 49)
                    ? x[xbase + (size_t)nrow * 50176 + (h0 + row / 7) * 224 + w0 + row % 7]
                    : 0.f;
                RV[row * LDA + nrow] = (bf16)(pacc[r] + bias + sc);   // raw t2
            }
        }
    }
    __syncthreads();

    // ---- LN2: stats + normalize, RV (raw t2) -> RB (LN2'd)
    {
        int r = tid >> 2, p = tid & 3;
        const int c0 = p * 24;
        const bf16* rp = &RV[r * LDA + c0];
        bf16x8 v0 = *(const bf16x8*)rp;
        bf16x8 v1 = *(const bf16x8*)(rp + 8);
        bf16x8 v2 = *(const bf16x8*)(rp + 16);
        float s = 0.f, s2 = 0.f;
#pragma unroll
        for (int j = 0; j < 8; ++j) {
            float a = (float)v0[j], c = (float)v1[j], d = (float)v2[j];
            s += a + c + d; s2 += a * a + c * c + d * d;
        }
        s += __shfl_xor(s, 1);  s2 += __shfl_xor(s2, 1);
        s += __shfl_xor(s, 2);  s2 += __shfl_xor(s2, 2);
        float mu = s * (1.f / 96.f);
        float rs = rsqrtf(fmaxf(s2 * (1.f / 96.f) - mu * mu, 0.f) + 1e-5f);
        bf16x8 o0, o1, o2;
#pragma unroll
        for (int j = 0; j < 8; ++j) {
            o0[j] = (bf16)(((float)v0[j] - mu) * rs * n2w[c0 + j] + n2b[c0 + j]);
            o1[j] = (bf16)(((float)v1[j] - mu) * rs * n2w[c0 + 8 + j] + n2b[c0 + 8 + j]);
            o2[j] = (bf16)(((float)v2[j] - mu) * rs * n2w[c0 + 16 + j] + n2b[c0 + 16 + j]);
        }
        bf16* wp = &RB[r * LDA + c0];
        *(bf16x8*)wp = o0; *(bf16x8*)(wp + 8) = o1; *(bf16x8*)(wp + 16) = o2;
    }
    __syncthreads();

    // ---- MLP: 4 hidden chunks of 96; A-frags streamed from LDS per k-step
    const int npt = (wave < 2) ? 2 : 1;
    f32x4 f2acc[2][4] = {{{0,0,0,0},{0,0,0,0},{0,0,0,0},{0,0,0,0}},
                         {{0,0,0,0},{0,0,0,0},{0,0,0,0},{0,0,0,0}}};
    for (int ch = 0; ch < 4; ++ch) {
        // fc1 chunk -> GELU -> RC
#pragma unroll
        for (int t = 0; t < 2; ++t) {
            if (t < npt) {
                int ntl = (t == 0) ? wave : wave + 4;
                int nrow = (ch * 6 + ntl) * 16 + q16;
                f32x4 acc[4] = {{0,0,0,0},{0,0,0,0},{0,0,0,0},{0,0,0,0}};
#pragma unroll
                for (int s = 0; s < 3; ++s) {
                    bf16x8 bf = bload(fc1T, fc1w, nrow, s * 32 + g * 8, 96, 384, wok);
#pragma unroll
                    for (int m = 0; m < 4; ++m) {
                        bf16x8 a = *(const bf16x8*)&RB[(m * 16 + q16) * LDA + s * 32 + g * 8];
                        acc[m] = mfma16(a, bf, acc[m]);
                    }
                }
                float bias = fc1b[nrow];
#pragma unroll
                for (int m = 0; m < 4; ++m)
#pragma unroll
                    for (int r = 0; r < 4; ++r)
                        RC[(m * 16 + g * 4 + r) * LDA + ntl * 16 + q16] =
                            (bf16)gelu_f(acc[m][r] + bias);
            }
        }
        __syncthreads();
        // fc2 partial-K accumulate; A-frags (hidden) streamed per s
#pragma unroll
        for (int s = 0; s < 3; ++s) {
            bf16x8 a0 = *(const bf16x8*)&RC[(q16)      * LDA + s * 32 + g * 8];
            bf16x8 a1 = *(const bf16x8*)&RC[(16 + q16) * LDA + s * 32 + g * 8];
            bf16x8 a2 = *(const bf16x8*)&RC[(32 + q16) * LDA + s * 32 + g * 8];
            bf16x8 a3 = *(const bf16x8*)&RC[(48 + q16) * LDA + s * 32 + g * 8];
#pragma unroll
            for (int t = 0; t < 2; ++t) {
                if (t < npt) {
                    int nt = (t == 0) ? wave : wave + 4;
                    int nrow = nt * 16 + q16;
                    bf16x8 bf = bload(fc2T, fc2w, nrow, ch * 96 + s * 32 + g * 8, 384, 96, wok);
                    f2acc[t][0] = mfma16(a0, bf, f2acc[t][0]);
                    f2acc[t][1] = mfma16(a1, bf, f2acc[t][1]);
                    f2acc[t][2] = mfma16(a2, bf, f2acc[t][2]);
                    f2acc[t][3] = mfma16(a3, bf, f2acc[t][3]);
                }
            }
        }
        __syncthreads();
    }

    // ---- final: out = raw t2 (RV) + fc2 + bias -> RV in place
#pragma unroll
    for (int t = 0; t < 2; ++t) {
        if (t < npt) {
            int col = ((t == 0) ? wave : wave + 4) * 16 + q16;
            float bias = fc2b[col];
#pragma unroll
            for (int m = 0; m < 4; ++m)
#pragma unroll
                for (int r = 0; r < 4; ++r) {
                    int row = m * 16 + g * 4 + r;
                    float t2 = (float)RV[row * LDA + col];
                    RV[row * LDA + col] = (bf16)(f2acc[t][m][r] + bias + t2);
                }
        }
    }
    __syncthreads();

    // ---- store (rows 0..48)
    if (fast) {
#pragma unroll
        for (int i = 0; i < 3; ++i) {
            int id = i * 256 + tid;
            if (id < 588) {
                int row = id / 12, c8 = id - row * 12;
                *(i32x4*)(tokW + (size_t)win * TOKW + row * 96 + c8 * 8) =
                    *(const i32x4*)&RV[row * LDA + c8 * 8];
            }
        }
    } else {
        for (int i = 0; i < 19; ++i) {
            int id = i * 256 + tid;
            if (id < 4704) {
                int c = id / 49, pix = id - c * 49;
                int ty = pix / 7, tx = pix - ty * 7;
                out[xbase + (size_t)c * 50176 + (h0 + ty) * 224 + w0 + tx] =
                    (float)RV[pix * LDA + c];
            }
        }
    }
}

// ---------------------------------------------------------------------------
extern "C" void kernel_launch(void* const* d_in, const int* in_sizes, int n_in,
                              void* d_out, int out_size, void* d_ws, size_t ws_size,
                              hipStream_t stream) {
    const float* x      = (const float*)d_in[0];
    const float* n1w    = (const float*)d_in[1];
    const float* n1b    = (const float*)d_in[2];
    const float* qkv_w  = (const float*)d_in[3];
    const float* qkv_b  = (const float*)d_in[4];
    const float* proj_w = (const float*)d_in[5];
    const float* proj_b = (const float*)d_in[6];
    const float* n2w    = (const float*)d_in[7];
    const float* n2b    = (const float*)d_in[8];
    const float* fc1_w  = (const float*)d_in[9];
    const float* fc1_b  = (const float*)d_in[10];
    const float* fc2_w  = (const float*)d_in[11];
    const float* fc2_b  = (const float*)d_in[12];
    float* out = (float*)d_out;

    const size_t TOKW_OFF = 225280;
    const int wok  = (ws_size >= 221184) ? 1 : 0;
    const int fast = (ws_size >= TOKW_OFF + 100663296ull) ? 1 : 0;
    bf16* wsT  = (bf16*)d_ws;
    bf16* tokW = (bf16*)((char*)d_ws + TOKW_OFF);

    if (wok)
        swin_wprep<<<dim3(432), dim3(256), 0, stream>>>(qkv_w, proj_w, fc1_w, fc2_w, wsT);
    if (fast) {
        swin_padfill<<<dim3(5760), dim3(256), 0, stream>>>(tokW);
        swin_gather<<<dim3(1792), dim3(256), 0, stream>>>(x, tokW);
    }
    swin_fused<<<dim3(8192), dim3(256), 0, stream>>>(
        x, tokW, n1w, n1b, qkv_w, qkv_b, proj_w, proj_b, n2w, n2b,
        fc1_w, fc1_b, fc2_w, fc2_b, wsT, out, fast, wok);
    if (fast)
        swin_scatter<<<dim3(1792), dim3(256), 0, stream>>>(tokW, out);
}